// Round 11
// baseline (22241.806 us; speedup 1.0000x reference)
//
#include <hip/hip_runtime.h>
#include <math.h>

#define DM    1024
#define NH    16
#define DKH   64
#define NL    4
#define DFFN  4096
#define BB    4
#define TT    1024
#define NSTEP 24
#define BT    (BB*TT)      // 4096 encoder rows
#define MD    (BB*NSTEP)   // 96 decoder rows max (packed: row = i*4 + b)
#define MDX   128          // padded rows for k_fattn speculative reads
#define CSPLIT 8
#define CKEYS  (TT/CSPLIT) // 128 keys per cross-attn split
#define NROW  96
#define PSTRIDE ((size_t)NROW*DM)      // FFN2 partial stride (f32)

typedef __attribute__((ext_vector_type(8))) short s16x8;
typedef __attribute__((ext_vector_type(4))) short s16x4;
typedef __attribute__((ext_vector_type(4))) float f32x4;

__device__ inline short f2b(float f){
  unsigned u = __float_as_uint(f);
  u += 0x7fffu + ((u>>16)&1u);          // round-to-nearest-even
  return (short)(u>>16);
}
__device__ inline float b2f(short h){
  return __uint_as_float(((unsigned)(unsigned short)h)<<16);
}

__device__ inline float wave_sum(float v){
  #pragma unroll
  for (int off=1; off<64; off<<=1) v += __shfl_xor(v, off, 64);
  return v;
}

// ---------------- f32 -> (hi,lo) bf16 split (row-major) ----------------
__global__ __launch_bounds__(256)
void split_kernel(const float* __restrict__ X, short* __restrict__ Hi,
                  short* __restrict__ Lo, int n8)
{
  const size_t i = (size_t)blockIdx.x*256 + threadIdx.x;
  if (i >= (size_t)n8) return;
  const float4 v0 = *(const float4*)(X + i*8);
  const float4 v1 = *(const float4*)(X + i*8 + 4);
  const float f[8] = {v0.x,v0.y,v0.z,v0.w,v1.x,v1.y,v1.z,v1.w};
  s16x8 hv, lv;
  #pragma unroll
  for (int e=0;e<8;e++){
    const short h = f2b(f[e]);
    hv[e] = h;
    lv[e] = f2b(f[e] - b2f(h));
  }
  *(s16x8*)(Hi + i*8) = hv;
  *(s16x8*)(Lo + i*8) = lv;
}

// f32 [N][K] row-major -> swizzled split: elem (row,k) at ((k>>3)*N+row)*8+(k&7)
__global__ __launch_bounds__(256)
void split_swz_kernel(const float* __restrict__ X, short* __restrict__ Hi,
                      short* __restrict__ Lo, int N, int K)
{
  const size_t idx = (size_t)blockIdx.x*256 + threadIdx.x;   // one 8-elem k-block
  const size_t total = (size_t)N*(K>>3);
  if (idx >= total) return;
  const int row = (int)(idx % (size_t)N);
  const int kb  = (int)(idx / (size_t)N);
  const float* src = X + (size_t)row*K + (size_t)kb*8;
  s16x8 hv, lv;
  #pragma unroll
  for (int e=0;e<8;e++){
    const float f = src[e];
    const short h = f2b(f);
    hv[e] = h;
    lv[e] = f2b(f - b2f(h));
  }
  *(s16x8*)(Hi + idx*8) = hv;
  *(s16x8*)(Lo + idx*8) = lv;
}

__global__ void zero_kernel(float* __restrict__ p, int n) {
  int i = blockIdx.x*256 + threadIdx.x;
  if (i < n) p[i] = 0.f;
}

// f32 1024x1024 transpose
__global__ __launch_bounds__(256)
void k_transpose(const float* __restrict__ A, float* __restrict__ At)
{
  __shared__ float tile[32][33];
  const int bx = blockIdx.x & 31, by = blockIdx.x >> 5;
  const int x0 = bx*32, y0 = by*32;
  const int tid = threadIdx.x;
  for (int i=tid; i<1024; i+=256){
    const int r = i>>5, c = i&31;
    tile[r][c] = A[(size_t)(y0+r)*DM + x0+c];
  }
  __syncthreads();
  for (int i=tid; i<1024; i+=256){
    const int r = i>>5, c = i&31;
    At[(size_t)(x0+r)*DM + y0+c] = tile[c][r];
  }
}

// bc[row] = dot(Wq[row,:], bo) + bq[row]
__global__ __launch_bounds__(256)
void k_bc(const float* __restrict__ Wq, const float* __restrict__ bo,
          const float* __restrict__ bq, float* __restrict__ bc)
{
  const int row = blockIdx.x, tid = threadIdx.x;
  float s = 0.f;
  for (int j=tid; j<DM; j+=256) s += Wq[(size_t)row*DM + j]*bo[j];
  s = wave_sum(s);
  __shared__ float r4[4];
  if ((tid&63)==0) r4[tid>>6] = s;
  __syncthreads();
  if (tid==0) bc[row] = r4[0]+r4[1]+r4[2]+r4[3] + bq[row];
}

// h[row] + pe[row%TT] -> split bf16 (encoder)
__global__ __launch_bounds__(256)
void add_pe_split(const float* __restrict__ h, short* __restrict__ Hi,
                  short* __restrict__ Lo)
{
  const int row = blockIdx.x;
  const int pos = row & (TT-1);
  const int d = threadIdx.x*4;
  const float4 a = *(const float4*)(h + (size_t)row*DM + d);
  const float c1 = -9.210340371976184f / 1024.0f;
  const float e0 = expf((float)d * c1);
  const float e1 = expf((float)(d+2) * c1);
  const float a0 = (float)pos * e0, a1 = (float)pos * e1;
  const float v[4] = {a.x + sinf(a0), a.y + cosf(a0), a.z + sinf(a1), a.w + cosf(a1)};
  s16x4 hv, lv;
  #pragma unroll
  for (int e=0;e<4;e++){
    const short hb = f2b(v[e]);
    hv[e] = hb;
    lv[e] = f2b(v[e] - b2f(hb));
  }
  *(s16x4*)(Hi + (size_t)row*DM + d) = hv;
  *(s16x4*)(Lo + (size_t)row*DM + d) = lv;
}

// ---------------- split-bf16 MFMA GEMM (encoder): C = A @ W^T + bias ----------
template<int ACT, int OUT_MODE>
__global__ __launch_bounds__(256, 2)
void gemm_split(const short* __restrict__ Ahi, const short* __restrict__ Alo,
                const short* __restrict__ Bhi, const short* __restrict__ Blo,
                const float* __restrict__ bias,
                float* __restrict__ C, short* __restrict__ Chi, short* __restrict__ Clo,
                int M, int N, int K)
{
  __shared__ __align__(16) short lA[2][128][40];
  __shared__ __align__(16) short lB[2][128][40];
  const int tid = threadIdx.x;
  const int m0 = blockIdx.x*128, n0 = blockIdx.y*128;
  const int lane = tid & 63, w = tid >> 6;
  const int wr = w >> 1, wc = w & 1;
  const int fr = lane & 15, fq = lane >> 4;

  f32x4 acc[4][4];
  #pragma unroll
  for (int i=0;i<4;i++)
    #pragma unroll
    for (int j=0;j<4;j++) acc[i][j] = (f32x4){0.f,0.f,0.f,0.f};

  for (int k0 = 0; k0 < K; k0 += 32) {
    __syncthreads();
    #pragma unroll
    for (int j=0;j<2;j++){
      const int cc = tid + j*256;
      const int row = cc >> 2, kq = cc & 3;
      const size_t ga = (size_t)(m0+row)*K + k0 + kq*8;
      const size_t gb = (size_t)(n0+row)*K + k0 + kq*8;
      *(s16x8*)&lA[0][row][kq*8] = *(const s16x8*)(Ahi + ga);
      *(s16x8*)&lA[1][row][kq*8] = *(const s16x8*)(Alo + ga);
      *(s16x8*)&lB[0][row][kq*8] = *(const s16x8*)(Bhi + gb);
      *(s16x8*)&lB[1][row][kq*8] = *(const s16x8*)(Blo + gb);
    }
    __syncthreads();
    s16x8 ah[4], al[4], bh[4], bl[4];
    #pragma unroll
    for (int i=0;i<4;i++){
      ah[i] = *(const s16x8*)&lA[0][wr*64+i*16+fr][fq*8];
      al[i] = *(const s16x8*)&lA[1][wr*64+i*16+fr][fq*8];
    }
    #pragma unroll
    for (int j=0;j<4;j++){
      bh[j] = *(const s16x8*)&lB[0][wc*64+j*16+fr][fq*8];
      bl[j] = *(const s16x8*)&lB[1][wc*64+j*16+fr][fq*8];
    }
    #pragma unroll
    for (int i=0;i<4;i++)
      #pragma unroll
      for (int j=0;j<4;j++){
        acc[i][j] = __builtin_amdgcn_mfma_f32_16x16x32_bf16(ah[i], bh[j], acc[i][j], 0,0,0);
        acc[i][j] = __builtin_amdgcn_mfma_f32_16x16x32_bf16(ah[i], bl[j], acc[i][j], 0,0,0);
        acc[i][j] = __builtin_amdgcn_mfma_f32_16x16x32_bf16(al[i], bh[j], acc[i][j], 0,0,0);
      }
  }
  #pragma unroll
  for (int j=0;j<4;j++){
    const int col = n0 + wc*64 + j*16 + fr;
    const float bv = bias[col];
    #pragma unroll
    for (int i=0;i<4;i++){
      const int row0 = m0 + wr*64 + i*16 + fq*4;
      #pragma unroll
      for (int r=0;r<4;r++){
        float v = acc[i][j][r] + bv;
        if (ACT==1) v = fmaxf(v, 0.f);
        const size_t idx = (size_t)(row0+r)*N + col;
        if (OUT_MODE==0 || OUT_MODE==2) C[idx] = v;
        if (OUT_MODE==1 || OUT_MODE==2){
          const short hb = f2b(v);
          Chi[idx] = hb;
          Clo[idx] = f2b(v - b2f(hb));
        }
        if (OUT_MODE==3) Chi[idx] = f2b(v);
      }
    }
  }
}

// ---------------- encoder self-attention ----
__global__ __launch_bounds__(256)
void attn_enc(const float* __restrict__ Qg, const float* __restrict__ Kg,
              const float* __restrict__ Vg, short* __restrict__ Ohi,
              short* __restrict__ Olo)
{
  const int bh = blockIdx.y;
  const int b = bh >> 4, hh = bh & 15;
  const int row = blockIdx.x*256 + threadIdx.x;
  const size_t base = ((size_t)b*TT)*DM + hh*DKH;
  float q[64];
  {
    const float* qp = Qg + base + (size_t)row*DM;
    #pragma unroll
    for (int d4=0; d4<16; d4++){
      const float4 v = *(const float4*)(qp + d4*4);
      q[d4*4+0]=v.x; q[d4*4+1]=v.y; q[d4*4+2]=v.z; q[d4*4+3]=v.w;
    }
  }
  float o[64];
  #pragma unroll
  for (int d=0;d<64;d++) o[d]=0.f;
  float m = -INFINITY, l = 0.f;
  __shared__ float Ks[64][68];
  __shared__ float Vs[64][68];
  for (int kt=0; kt<TT; kt+=64) {
    __syncthreads();
    #pragma unroll
    for (int t=0;t<4;t++){
      const int fi = threadIdx.x + t*256;
      const int j = fi>>4, dq = fi&15;
      *(float4*)&Ks[j][dq*4] = *(const float4*)(Kg + base + (size_t)(kt+j)*DM + dq*4);
      *(float4*)&Vs[j][dq*4] = *(const float4*)(Vg + base + (size_t)(kt+j)*DM + dq*4);
    }
    __syncthreads();
    for (int j=0;j<64;j++){
      float s0=0.f,s1=0.f,s2=0.f,s3=0.f;
      #pragma unroll
      for (int d=0; d<64; d+=4){
        s0 = fmaf(q[d+0], Ks[j][d+0], s0);
        s1 = fmaf(q[d+1], Ks[j][d+1], s1);
        s2 = fmaf(q[d+2], Ks[j][d+2], s2);
        s3 = fmaf(q[d+3], Ks[j][d+3], s3);
      }
      const float s = ((s0+s1)+(s2+s3)) * 0.125f;
      if (s > m) {
        const float f = __expf(m - s);
        l *= f;
        #pragma unroll
        for (int d=0;d<64;d++) o[d] *= f;
        m = s;
      }
      const float p = __expf(s - m);
      l += p;
      #pragma unroll
      for (int d=0;d<64;d++) o[d] = fmaf(p, Vs[j][d], o[d]);
    }
  }
  const float inv = 1.f / l;
  #pragma unroll
  for (int d8=0; d8<8; d8++){
    s16x8 hv, lv;
    #pragma unroll
    for (int e=0;e<8;e++){
      const float f = o[d8*8+e]*inv;
      const short hb = f2b(f);
      hv[e] = hb;
      lv[e] = f2b(f - b2f(hb));
    }
    *(s16x8*)(Ohi + base + (size_t)row*DM + d8*8) = hv;
    *(s16x8*)(Olo + base + (size_t)row*DM + d8*8) = lv;
  }
}

// encoder LayerNorm: split bf16 out
__global__ __launch_bounds__(256)
void ln_add_split(const float* __restrict__ X, const float* __restrict__ Y,
                  const float* __restrict__ g, const float* __restrict__ be,
                  short* __restrict__ Ohi, short* __restrict__ Olo)
{
  const size_t row = blockIdx.x;
  const int tid = threadIdx.x;
  const float4 a = *(const float4*)(X + row*DM + tid*4);
  const float4 b = *(const float4*)(Y + row*DM + tid*4);
  const float v0=a.x+b.x, v1=a.y+b.y, v2=a.z+b.z, v3=a.w+b.w;
  float s = v0+v1+v2+v3;
  float q = v0*v0+v1*v1+v2*v2+v3*v3;
  s = wave_sum(s); q = wave_sum(q);
  __shared__ float rs[4], rq[4];
  if ((tid&63)==0){ rs[tid>>6]=s; rq[tid>>6]=q; }
  __syncthreads();
  const float S = rs[0]+rs[1]+rs[2]+rs[3];
  const float Q = rq[0]+rq[1]+rq[2]+rq[3];
  const float mean = S * (1.f/DM);
  const float var  = Q * (1.f/DM) - mean*mean;
  const float rstd = rsqrtf(var + 1e-5f);
  const float4 gv = *(const float4*)(g  + tid*4);
  const float4 bv = *(const float4*)(be + tid*4);
  const float v[4] = {(v0-mean)*rstd*gv.x + bv.x, (v1-mean)*rstd*gv.y + bv.y,
                      (v2-mean)*rstd*gv.z + bv.z, (v3-mean)*rstd*gv.w + bv.w};
  s16x4 hv, lv;
  #pragma unroll
  for (int e=0;e<4;e++){
    const short hb = f2b(v[e]);
    hv[e] = hb;
    lv[e] = f2b(v[e] - b2f(hb));
  }
  *(s16x4*)(Ohi + row*DM + tid*4) = hv;
  *(s16x4*)(Olo + row*DM + tid*4) = lv;
}

// ================= decoder (stream-launched, swizzled weights) =================

__device__ inline f32x4 mfma3(const s16x8 ah, const s16x8 al,
                              const s16x8 bh, const s16x8 bl, f32x4 A){
  A = __builtin_amdgcn_mfma_f32_16x16x32_bf16(ah, bh, A, 0,0,0);
  A = __builtin_amdgcn_mfma_f32_16x16x32_bf16(ah, bl, A, 0,0,0);
  A = __builtin_amdgcn_mfma_f32_16x16x32_bf16(al, bh, A, 0,0,0);
  return A;
}

// 16-col-tile GEMM, 4-wave K-split, A row-major, B SWIZZLED (k-block-major).
// MODE bit0: f32 out, bit1: split out. bias nullable. mr = #16-row frags (1..6).
template<int MODE, int ACT, int CHUNKS>
__device__ inline void gemm16(const short* __restrict__ Ahi, const short* __restrict__ Alo,
    const short* __restrict__ Bhi, const short* __restrict__ Blo,
    int lda, int nbr /* B total rows */, int ldo, int c0, int kbase, int mr,
    const float* __restrict__ bias,
    float* __restrict__ outf, short* __restrict__ ohi, short* __restrict__ olo,
    float (*red)[96][17])
{
  const int tid = threadIdx.x, lane = tid & 63, w = tid >> 6;
  const int fr = lane & 15, fq = lane >> 4;
  const size_t kw = (size_t)kbase + w*(CHUNKS*32) + fq*8;
  const short* Ah = Ahi + (size_t)fr*lda + kw;
  const short* Al = Alo + (size_t)fr*lda + kw;
  const size_t bb = ((kw>>3)*(size_t)nbr + (size_t)(c0+fr))*8;
  const short* Bh = Bhi + bb;
  const short* Bl = Blo + bb;
  const size_t bstep = (size_t)4*nbr*8;       // 4 k-blocks per 32-wide chunk
  f32x4 a0={0.f,0.f,0.f,0.f}, a1=a0, a2=a0, a3=a0, a4=a0, a5=a0;
  #pragma unroll
  for (int c=0; c<CHUNKS; c++){
    const s16x8 bh = *(const s16x8*)(Bh + (size_t)c*bstep);
    const s16x8 bl = *(const s16x8*)(Bl + (size_t)c*bstep);
    const int ko = c*32;
    #define AS(i, A) if (mr > i){ \
      const s16x8 ah = *(const s16x8*)(Ah + (size_t)(i*16)*lda + ko); \
      const s16x8 al = *(const s16x8*)(Al + (size_t)(i*16)*lda + ko); \
      A = mfma3(ah, al, bh, bl, A); }
    AS(0,a0) AS(1,a1) AS(2,a2) AS(3,a3) AS(4,a4) AS(5,a5)
    #undef AS
  }
  #define ST(i, A) if (mr > i){ \
    red[w][i*16+fq*4+0][fr]=A[0]; red[w][i*16+fq*4+1][fr]=A[1]; \
    red[w][i*16+fq*4+2][fr]=A[2]; red[w][i*16+fq*4+3][fr]=A[3]; }
  ST(0,a0) ST(1,a1) ST(2,a2) ST(3,a3) ST(4,a4) ST(5,a5)
  #undef ST
  __syncthreads();
  const int tot = mr*256;
  for (int o=tid; o<tot; o+=256){
    const int row = o >> 4, col = o & 15;
    float s = red[0][row][col] + red[1][row][col] + red[2][row][col] + red[3][row][col];
    if (bias) s += bias[c0 + col];
    if (ACT) s = fmaxf(s, 0.f);
    const size_t idx = (size_t)row*ldo + c0 + col;
    if (MODE & 1) outf[idx] = s;
    if (MODE & 2){
      const short hb = f2b(s);
      ohi[idx] = hb;
      olo[idx] = f2b(s - b2f(hb));
    }
  }
}

// fused per-head QKV projection + self-attention. 64 blocks = (b,hh).
__global__ __launch_bounds__(256)
void k_fattn(const short* __restrict__ inhi, const short* __restrict__ inlo,
             const short* __restrict__ wqh, const short* __restrict__ wql,
             const short* __restrict__ wkh, const short* __restrict__ wkl,
             const short* __restrict__ wvh, const short* __restrict__ wvl,
             const float* __restrict__ bq, const float* __restrict__ bk,
             const float* __restrict__ bv,
             short* __restrict__ Ohi, short* __restrict__ Olo, int n)
{
  const int bh = blockIdx.x, b = bh >> 4, hh = bh & 15;
  __shared__ float Qs[NSTEP][68], Ks[NSTEP][68], Vs[NSTEP][68];
  __shared__ float P[NSTEP][28];
  __shared__ float red[4][32][17];
  const int tid = threadIdx.x, lane = tid & 63, w = tid >> 6;
  const int fr = lane & 15, fq = lane >> 4;
  const int mr2 = (n > 16) ? 2 : 1;
  const int lda = 4*DM;                         // gather batch b: packed row i*4+b
  const size_t kw = (size_t)w*256 + fq*8;
  const short* Ah = inhi + (size_t)b*DM + (size_t)fr*lda + kw;
  const short* Al = inlo + (size_t)b*DM + (size_t)fr*lda + kw;
  #pragma unroll
  for (int mat=0; mat<3; ++mat){
    const short* Bh = mat==0?wqh:(mat==1?wkh:wvh);
    const short* Bl = mat==0?wql:(mat==1?wkl:wvl);
    const float* bias = mat==0?bq:(mat==1?bk:bv);
    float (*dst)[68] = mat==0?Qs:(mat==1?Ks:Vs);
    for (int sub=0; sub<4; ++sub){
      const int c0 = hh*64 + sub*16;
      const size_t bb = ((kw>>3)*(size_t)DM + (size_t)(c0+fr))*8;
      f32x4 a0={0.f,0.f,0.f,0.f}, a1=a0;
      #pragma unroll
      for (int c=0;c<8;c++){
        const s16x8 bhv = *(const s16x8*)(Bh + bb + (size_t)c*4*DM*8);
        const s16x8 blv = *(const s16x8*)(Bl + bb + (size_t)c*4*DM*8);
        {
          const s16x8 ah = *(const s16x8*)(Ah + c*32);
          const s16x8 al = *(const s16x8*)(Al + c*32);
          a0 = mfma3(ah, al, bhv, blv, a0);
        }
        if (mr2 > 1){
          const s16x8 ah = *(const s16x8*)(Ah + (size_t)16*lda + c*32);
          const s16x8 al = *(const s16x8*)(Al + (size_t)16*lda + c*32);
          a1 = mfma3(ah, al, bhv, blv, a1);
        }
      }
      __syncthreads();                          // red free (prev sub's readers done)
      #pragma unroll
      for (int r=0;r<4;r++){
        red[w][fq*4+r][fr] = a0[r];
        if (mr2 > 1) red[w][16+fq*4+r][fr] = a1[r];
      }
      __syncthreads();
      for (int o=tid; o<n*16; o+=256){
        const int row = o >> 4, col = o & 15;
        const float s = red[0][row][col]+red[1][row][col]+red[2][row][col]
                      + red[3][row][col] + bias[c0+col];
        dst[row][sub*16+col] = s;
      }
    }
  }
  __syncthreads();
  for (int idx = tid; idx < n*n; idx += 256){
    const int i = idx / n, j = idx - i*n;
    float s0=0.f,s1=0.f,s2=0.f,s3=0.f;
    #pragma unroll
    for (int d=0; d<64; d+=4){
      s0 = fmaf(Qs[i][d+0], Ks[j][d+0], s0);
      s1 = fmaf(Qs[i][d+1], Ks[j][d+1], s1);
      s2 = fmaf(Qs[i][d+2], Ks[j][d+2], s2);
      s3 = fmaf(Qs[i][d+3], Ks[j][d+3], s3);
    }
    P[i][j] = ((s0+s1)+(s2+s3))*0.125f;
  }
  __syncthreads();
  if (tid < n){
    float mm = -INFINITY;
    for (int j=0;j<n;j++) mm = fmaxf(mm, P[tid][j]);
    float l = 0.f;
    for (int j=0;j<n;j++){ const float p = __expf(P[tid][j]-mm); P[tid][j]=p; l+=p; }
    const float inv = 1.f/l;
    for (int j=0;j<n;j++) P[tid][j] *= inv;
  }
  __syncthreads();
  const size_t obase = (size_t)b*DM + hh*DKH;
  for (int idx = tid; idx < n*64; idx += 256){
    const int i = idx >> 6, d = idx & 63;
    float s = 0.f;
    for (int j=0;j<n;j++) s = fmaf(P[i][j], Vs[j][d], s);
    const short hb = f2b(s);
    const size_t o = obase + (size_t)(i*4)*DM + d;
    Ohi[o] = hb;
    Olo[o] = f2b(s - b2f(hb));
  }
}

// generic 64-block projection (K=1024), swizzled B
template<int MODE>
__global__ __launch_bounds__(256)
void k_proj(const short* __restrict__ Ahi, const short* __restrict__ Alo,
            const short* __restrict__ Bh, const short* __restrict__ Bl,
            const float* __restrict__ bias,
            float* __restrict__ outf, short* __restrict__ ohi, short* __restrict__ olo,
            int mr)
{
  __shared__ __align__(16) float red[4][96][17];
  gemm16<MODE,0,8>(Ahi, Alo, Bh, Bl, DM, DM, DM, blockIdx.x*16, 0, mr,
                   bias, outf, ohi, olo, red);
}

// FFN1: 256 blocks, relu + split out
__global__ __launch_bounds__(256)
void k_ffn1(const short* __restrict__ Ahi, const short* __restrict__ Alo,
            const short* __restrict__ Bh, const short* __restrict__ Bl,
            const float* __restrict__ bias,
            short* __restrict__ ohi, short* __restrict__ olo, int mr)
{
  __shared__ __align__(16) float red[4][96][17];
  gemm16<2,1,8>(Ahi, Alo, Bh, Bl, DM, DFFN, DFFN, blockIdx.x*16, 0, mr,
                bias, nullptr, ohi, olo, red);
}

// FFN2: grid (64, 2): K=4096 split in two halves -> f32 partials, no bias
__global__ __launch_bounds__(256)
void k_ffn2(const short* __restrict__ Ahi, const short* __restrict__ Alo,
            const short* __restrict__ Bh, const short* __restrict__ Bl,
            float* __restrict__ part, int mr)
{
  __shared__ __align__(16) float red[4][96][17];
  gemm16<1,0,16>(Ahi, Alo, Bh, Bl, DFFN, DM, DM, blockIdx.x*16,
                 blockIdx.y*2048, mr,
                 nullptr, part + (size_t)blockIdx.y*PSTRIDE, nullptr, nullptr, red);
}

// cross-attn partials: grid (CSPLIT, 64)
__global__ __launch_bounds__(256)
void k_cross_part(const float* __restrict__ Qg, const short* __restrict__ Kc,
                  const short* __restrict__ Vc, float* __restrict__ opart,
                  float* __restrict__ mlpart, int n)
{
  const int ks = blockIdx.x, bh = blockIdx.y;
  const int b = bh >> 4, hh = bh & 15;
  __shared__ float Qs[NSTEP][68];
  __shared__ short KVs[CKEYS][72];
  __shared__ float S[NSTEP][132];
  const int tid = threadIdx.x;
  const size_t qbase = (size_t)b*DM + hh*DKH;
  for (int t=tid; t<n*16; t+=256){
    const int row = t>>4, q4 = t&15;
    *(float4*)&Qs[row][q4*4] = *(const float4*)(Qg + qbase + (size_t)(row*4)*DM + q4*4);
  }
  const size_t kbase = ((size_t)b*TT + (size_t)ks*CKEYS)*DM + hh*DKH;
  for (int t=tid; t<CKEYS*8; t+=256){
    const int row = t>>3, d8 = t&7;
    *(s16x8*)&KVs[row][d8*8] = *(const s16x8*)(Kc + kbase + (size_t)row*DM + d8*8);
  }
  __syncthreads();
  for (int idx=tid; idx<n*128; idx+=256){
    const int i = idx >> 7, j = idx & 127;
    float s0=0.f,s1=0.f,s2=0.f,s3=0.f;
    #pragma unroll
    for (int d=0; d<64; d+=4){
      s0 = fmaf(Qs[i][d+0], b2f(KVs[j][d+0]), s0);
      s1 = fmaf(Qs[i][d+1], b2f(KVs[j][d+1]), s1);
      s2 = fmaf(Qs[i][d+2], b2f(KVs[j][d+2]), s2);
      s3 = fmaf(Qs[i][d+3], b2f(KVs[j][d+3]), s3);
    }
    S[i][j] = ((s0+s1)+(s2+s3))*0.125f;
  }
  __syncthreads();
  for (int t=tid; t<CKEYS*8; t+=256){
    const int row = t>>3, d8 = t&7;
    *(s16x8*)&KVs[row][d8*8] = *(const s16x8*)(Vc + kbase + (size_t)row*DM + d8*8);
  }
  if (tid < n){
    float mm=-INFINITY;
    for (int j=0;j<CKEYS;j++) mm = fmaxf(mm, S[tid][j]);
    float l=0.f;
    for (int j=0;j<CKEYS;j++){ const float p=__expf(S[tid][j]-mm); S[tid][j]=p; l+=p; }
    mlpart[((size_t)bh*CSPLIT+ks)*(2*NSTEP) + tid*2+0] = mm;
    mlpart[((size_t)bh*CSPLIT+ks)*(2*NSTEP) + tid*2+1] = l;
  }
  __syncthreads();
  for (int idx=tid; idx<n*64; idx+=256){
    const int i = idx >> 6, d = idx & 63;
    float s=0.f;
    for (int j=0;j<CKEYS;j++) s = fmaf(S[i][j], b2f(KVs[j][d]), s);
    opart[(((size_t)bh*CSPLIT+ks)*NSTEP + i)*DKH + d] = s;
  }
}

// combine: 64 blocks
__global__ __launch_bounds__(256)
void k_comb(const float* __restrict__ opart, const float* __restrict__ mlp,
            short* __restrict__ Ohi, short* __restrict__ Olo, int n)
{
  const int bh = blockIdx.x;
  const int b = bh >> 4, hh = bh & 15;
  for (int idx=threadIdx.x; idx<n*64; idx+=256){
    const int i = idx >> 6, d = idx & 63;
    float M = -INFINITY;
    #pragma unroll
    for (int s=0;s<CSPLIT;s++)
      M = fmaxf(M, mlp[((size_t)bh*CSPLIT+s)*(2*NSTEP) + i*2]);
    float acc = 0.f, L = 0.f;
    #pragma unroll
    for (int s=0;s<CSPLIT;s++){
      const float mm = mlp[((size_t)bh*CSPLIT+s)*(2*NSTEP) + i*2+0];
      const float ll = mlp[((size_t)bh*CSPLIT+s)*(2*NSTEP) + i*2+1];
      const float f = __expf(mm - M);
      acc = fmaf(f, opart[(((size_t)bh*CSPLIT+s)*NSTEP + i)*DKH + d], acc);
      L   = fmaf(f, ll, L);
    }
    const float v = acc / L;
    const short hb = f2b(v);
    const size_t o = ((size_t)(i*4+b))*DM + hh*DKH + d;
    Ohi[o] = hb;
    Olo[o] = f2b(v - b2f(hb));
  }
}

// reduce FFN2 partials(2) + bias + residual -> LN -> dbuf f32 + split. rows blocks.
__global__ __launch_bounds__(256)
void k_ln(const float* __restrict__ part, const float* __restrict__ bias,
          const float* __restrict__ X, const float* __restrict__ g,
          const float* __restrict__ be,
          float* __restrict__ Outf, short* __restrict__ Ohi, short* __restrict__ Olo)
{
  const int row = blockIdx.x;
  __shared__ float rs[4], rq[4];
  const int tid = threadIdx.x;
  const float4 p0 = *(const float4*)(part + (size_t)row*DM + tid*4);
  const float4 p1 = *(const float4*)(part + PSTRIDE + (size_t)row*DM + tid*4);
  const float4 bvv = *(const float4*)(bias + tid*4);
  const float4 xv  = *(const float4*)(X + (size_t)row*DM + tid*4);
  const float v0=p0.x+p1.x+bvv.x+xv.x, v1=p0.y+p1.y+bvv.y+xv.y;
  const float v2=p0.z+p1.z+bvv.z+xv.z, v3=p0.w+p1.w+bvv.w+xv.w;
  float s = v0+v1+v2+v3;
  float q = v0*v0+v1*v1+v2*v2+v3*v3;
  s = wave_sum(s); q = wave_sum(q);
  if ((tid&63)==0){ rs[tid>>6]=s; rq[tid>>6]=q; }
  __syncthreads();
  const float S = rs[0]+rs[1]+rs[2]+rs[3];
  const float Q = rq[0]+rq[1]+rq[2]+rq[3];
  const float mean = S * (1.f/DM);
  const float var  = Q * (1.f/DM) - mean*mean;
  const float rstd = rsqrtf(var + 1e-5f);
  const float4 gv = *(const float4*)(g  + tid*4);
  const float4 bv2 = *(const float4*)(be + tid*4);
  const float v[4] = {(v0-mean)*rstd*gv.x + bv2.x, (v1-mean)*rstd*gv.y + bv2.y,
                      (v2-mean)*rstd*gv.z + bv2.z, (v3-mean)*rstd*gv.w + bv2.w};
  float4 of; of.x=v[0]; of.y=v[1]; of.z=v[2]; of.w=v[3];
  *(float4*)(Outf + (size_t)row*DM + tid*4) = of;
  s16x4 hv, lv;
  #pragma unroll
  for (int e=0;e<4;e++){
    const short hb = f2b(v[e]);
    hv[e] = hb;
    lv[e] = f2b(v[e] - b2f(hb));
  }
  *(s16x4*)(Ohi + (size_t)row*DM + tid*4) = hv;
  *(s16x4*)(Olo + (size_t)row*DM + tid*4) = lv;
}

// final projection + write next step's split input (emb + PE). 4 blocks.
__global__ __launch_bounds__(256)
void k_out(const float* __restrict__ Dv, const float* __restrict__ outW,
           const float* __restrict__ outB, const float* __restrict__ tembW,
           const float* __restrict__ tembB, float* __restrict__ dout,
           short* __restrict__ Dphi, short* __restrict__ Dplo, int s)
{
  const int b = blockIdx.x;
  __shared__ float red[4];
  __shared__ float stepv;
  const int tid = threadIdx.x;
  const float* drow = Dv + ((size_t)(s*4 + b))*DM;
  const float4 dv4 = *(const float4*)(drow + tid*4);
  const float4 wv = *(const float4*)(outW + tid*4);
  float p = dv4.x*wv.x + dv4.y*wv.y + dv4.z*wv.z + dv4.w*wv.w;
  p = wave_sum(p);
  if ((tid&63)==0) red[tid>>6] = p;
  __syncthreads();
  if (tid==0){
    const float sv = red[0]+red[1]+red[2]+red[3] + outB[0];
    stepv = sv;
    dout[b*NSTEP + s] = sv;
  }
  __syncthreads();
  const float sv = stepv;
  if (s+1 < NSTEP){
    const int d = tid*4, pos = s+1;
    const float4 tw = *(const float4*)(tembW + d);
    const float4 tb = *(const float4*)(tembB + d);
    const float c1 = -9.210340371976184f / 1024.0f;
    const float e0 = expf((float)d * c1);
    const float e1 = expf((float)(d+2) * c1);
    const float a0 = (float)pos * e0, a1 = (float)pos * e1;
    const float v[4] = { fmaf(sv, tw.x, tb.x) + sinf(a0),
                         fmaf(sv, tw.y, tb.y) + cosf(a0),
                         fmaf(sv, tw.z, tb.z) + sinf(a1),
                         fmaf(sv, tw.w, tb.w) + cosf(a1) };
    s16x4 hv, lv;
    #pragma unroll
    for (int e=0;e<4;e++){
      const short hb = f2b(v[e]);
      hv[e] = hb;
      lv[e] = f2b(v[e] - b2f(hb));
    }
    const size_t o = (size_t)(pos*4 + b)*DM + d;
    *(s16x4*)(Dphi + o) = hv;
    *(s16x4*)(Dplo + o) = lv;
  }
}

// step-0 input rows: split(0 + pe[0])
__global__ __launch_bounds__(256)
void k_init0(short* __restrict__ Dphi, short* __restrict__ Dplo)
{
  const int b = blockIdx.x;
  const int d = threadIdx.x*4;
  const float v[4] = {0.f, 1.f, 0.f, 1.f};   // sin(0), cos(0)
  s16x4 hv, lv;
  #pragma unroll
  for (int e=0;e<4;e++){
    const short hb = f2b(v[e]);
    hv[e] = hb;
    lv[e] = f2b(v[e] - b2f(hb));
  }
  *(s16x4*)(Dphi + (size_t)b*DM + d) = hv;
  *(s16x4*)(Dplo + (size_t)b*DM + d) = lv;
}

// ---------------- orchestration ----------------
extern "C" void kernel_launch(void* const* d_in, const int* in_sizes, int n_in,
                              void* d_out, int out_size, void* d_ws, size_t ws_size,
                              hipStream_t stream)
{
  (void)in_sizes; (void)n_in; (void)out_size; (void)ws_size;
  const float* x      = (const float*)d_in[0];
  const float* in_W   = (const float*)d_in[1];
  const float* in_b   = (const float*)d_in[2];
  const float* enc_Wq = (const float*)d_in[3];
  const float* enc_bq = (const float*)d_in[4];
  const float* enc_Wk = (const float*)d_in[5];
  const float* enc_bk = (const float*)d_in[6];
  const float* enc_Wv = (const float*)d_in[7];
  const float* enc_bv = (const float*)d_in[8];
  const float* enc_Wo = (const float*)d_in[9];
  const float* enc_bo = (const float*)d_in[10];
  const float* dec_Wq = (const float*)d_in[11];
  const float* dec_bq = (const float*)d_in[12];
  const float* dec_Wk = (const float*)d_in[13];
  const float* dec_bk = (const float*)d_in[14];
  const float* dec_Wv = (const float*)d_in[15];
  const float* dec_bv = (const float*)d_in[16];
  const float* dec_Wo = (const float*)d_in[17];
  const float* dec_bo = (const float*)d_in[18];
  const float* ffe_W1 = (const float*)d_in[19];
  const float* ffe_b1 = (const float*)d_in[20];
  const float* ffe_W2 = (const float*)d_in[21];
  const float* ffe_b2 = (const float*)d_in[22];
  const float* ffd_W1 = (const float*)d_in[23];
  const float* ffd_b1 = (const float*)d_in[24];
  const float* ffd_W2 = (const float*)d_in[25];
  const float* ffd_b2 = (const float*)d_in[26];
  const float* ne_g   = (const float*)d_in[27];
  const float* ne_b   = (const float*)d_in[28];
  const float* nd_g   = (const float*)d_in[29];
  const float* nd_b   = (const float*)d_in[30];
  const float* out_W  = (const float*)d_in[31];
  const float* out_b  = (const float*)d_in[32];
  const float* temb_W = (const float*)d_in[33];
  const float* temb_b = (const float*)d_in[34];
  float* dout = (float*)d_out;

  float* ws = (float*)d_ws;
  size_t off = 0;
  auto alloc  = [&](size_t n){ n = (n+3)&~(size_t)3; float* p = ws + off; off += n; return p; };
  auto allocS = [&](size_t n){ size_t nf = ((n+1)/2 + 3)&~(size_t)3; short* p = (short*)(ws + off); off += nf; return p; };

  // activations (encoder)
  short* hshi = allocS((size_t)BT*DM);
  short* hslo = allocS((size_t)BT*DM);
  float* h    = alloc((size_t)BT*DM);
  float* hn   = h;
  float* t0   = alloc((size_t)BT*DM);
  float* t1   = alloc((size_t)BT*DM);
  float* t2   = alloc((size_t)BT*DM);
  short* t3hi = allocS((size_t)BT*DM);
  short* t3lo = allocS((size_t)BT*DM);
  short* hnhi = allocS((size_t)BT*DM);
  short* hnlo = allocS((size_t)BT*DM);
  float* t4   = alloc((size_t)BT*DM);   // encoder FFN2 out UNION {wotf,wcf setup} UNION {dec part, opart, mlp}
  float* part = t4;
  short* fmhi = (short*)t0;
  short* fmlo = fmhi + (size_t)BT*DFFN;
  // bf16 K/V cross-attn cache
  short* kcb  = allocS((size_t)NL*BT*DM);
  short* vcb  = allocS((size_t)NL*BT*DM);
  // split inputs
  short* xshi = allocS((size_t)BT*64);
  short* xslo = allocS((size_t)BT*64);
  short* iwhi = allocS((size_t)DM*64);
  short* iwlo = allocS((size_t)DM*64);
  // per-layer reused weight slots
  short* w0hi = allocS((size_t)DM*DM); short* w0lo = allocS((size_t)DM*DM);
  short* w1hi = allocS((size_t)DM*DM); short* w1lo = allocS((size_t)DM*DM);
  short* w2hi = allocS((size_t)DM*DM); short* w2lo = allocS((size_t)DM*DM);
  short* w3hi = allocS((size_t)DM*DM); short* w3lo = allocS((size_t)DM*DM);
  short* wfhi = allocS((size_t)DFFN*DM); short* wflo = allocS((size_t)DFFN*DM);   // ffe_W1
  short* wf2hi= allocS((size_t)DM*DFFN); short* wf2lo= allocS((size_t)DM*DFFN);   // ffe_W2
  // combined cross-Q weights ALIAS dead-after-encoder ffe_W1 slots (exact fit: NL*MM == DFFN*DM)
  short* wqoh = wfhi; short* wqol = wflo;
  float* bqo  = alloc((size_t)NL*DM);
  float* zbuf = alloc((size_t)DM);
  // decoder buffers (packed rows r = i*4+b); k_fattn inputs padded to MDX rows
  float* dq   = alloc((size_t)MD*DM);
  float* dbuf = alloc((size_t)MD*DM);
  short* dphi = allocS((size_t)MDX*DM); short* dplo = allocS((size_t)MDX*DM);  // step input
  short* dlhi = allocS((size_t)MDX*DM); short* dllo = allocS((size_t)MDX*DM);  // LN out
  short* dxhi = allocS((size_t)MD*DM);  short* dxlo = allocS((size_t)MD*DM);   // cross-O out
  short* dahi = allocS((size_t)MD*DM);  short* dalo = allocS((size_t)MD*DM);   // attn out
  short* dmhi = allocS((size_t)MD*DFFN);short* dmlo = allocS((size_t)MD*DFFN);
  // opart/mlp live in t4 at offset 2M floats (disjoint from dec FFN2 partials [0,2*PSTRIDE))
  float* opart = t4 + (size_t)2*1024*1024;
  float* mlp   = opart + (size_t)BB*NH*CSPLIT*NSTEP*DKH;

  // decoder swizzled weights aliased onto dead-after-encoder buffers
  const size_t MM = (size_t)DM*DM;
  short* dwq = (short*)t0;
  short* dwk = (short*)t1;
  short* dwv = (short*)t2;
  short* dwo = (short*)h;
  short* fw1h = t3hi; short* fw1l = t3lo;
  short* fw2h = hnhi; short* fw2l = hnlo;
  float* wotf = t4;              // 4MB f32 temp (WoT), setup-phase only
  float* wcf  = t4 + MM;         // 4MB f32 temp (Wc), setup-phase only

  auto cvt = [&](const float* src, short* hi, short* lo, size_t n){
    split_kernel<<<(int)((n/8 + 255)/256), 256, 0, stream>>>(src, hi, lo, (int)(n/8));
  };
  auto swz = [&](const float* src, short* hi, short* lo, int N, int K){
    const size_t total = (size_t)N*(K>>3);
    split_swz_kernel<<<(int)((total + 255)/256), 256, 0, stream>>>(src, hi, lo, N, K);
  };

  cvt(x,    xshi, xslo, (size_t)BT*64);
  cvt(in_W, iwhi, iwlo, (size_t)DM*64);
  cvt(ffe_W1, wfhi,  wflo,  (size_t)DFFN*DM);
  cvt(ffe_W2, wf2hi, wf2lo, (size_t)DM*DFFN);
  zero_kernel<<<(DM+255)/256, 256, 0, stream>>>(zbuf, DM);

  // input projection + PE -> split
  gemm_split<0,0><<<dim3(BT/128, DM/128), 256, 0, stream>>>(
      xshi, xslo, iwhi, iwlo, in_b, h, (short*)nullptr, (short*)nullptr, BT, DM, 64);
  add_pe_split<<<BT, 256, 0, stream>>>(h, hshi, hslo);

  // ---- encoder ----
  for (int l=0; l<NL; ++l) {
    const size_t wo = (size_t)l*DM*DM, bo_ = (size_t)l*DM;
    cvt(enc_Wq+wo, w0hi, w0lo, MM);
    cvt(enc_Wk+wo, w1hi, w1lo, MM);
    cvt(enc_Wv+wo, w2hi, w2lo, MM);
    cvt(enc_Wo+wo, w3hi, w3lo, MM);
    gemm_split<0,0><<<dim3(32,8),256,0,stream>>>(hshi, hslo, w0hi, w0lo, enc_bq+bo_,
        t0, (short*)nullptr, (short*)nullptr, BT, DM, DM);
    gemm_split<0,0><<<dim3(32,8),256,0,stream>>>(hshi, hslo, w1hi, w1lo, enc_bk+bo_,
        t1, (short*)nullptr, (short*)nullptr, BT, DM, DM);
    gemm_split<0,0><<<dim3(32,8),256,0,stream>>>(hshi, hslo, w2hi, w2lo, enc_bv+bo_,
        t2, (short*)nullptr, (short*)nullptr, BT, DM, DM);
    attn_enc<<<dim3(TT/256, BB*NH),256,0,stream>>>(t0, t1, t2, t3hi, t3lo);
    gemm_split<0,2><<<dim3(32,8),256,0,stream>>>(t3hi, t3lo, w3hi, w3lo, enc_bo+bo_,
        hn, hnhi, hnlo, BT, DM, DM);
    gemm_split<1,1><<<dim3(32,32),256,0,stream>>>(hnhi, hnlo, wfhi, wflo, ffe_b1,
        (float*)nullptr, fmhi, fmlo, BT, DFFN, DM);
    gemm_split<0,0><<<dim3(32,8),256,0,stream>>>(fmhi, fmlo, wf2hi, wf2lo, ffe_b2,
        t4, (short*)nullptr, (short*)nullptr, BT, DM, DFFN);
    ln_add_split<<<BT,256,0,stream>>>(hn, t4, ne_g, ne_b, hshi, hslo);
  }

  // ---- cross-attention K/V cache (bf16) ----
  for (int l=0; l<NL; ++l) {
    const size_t wo = (size_t)l*DM*DM, bo_ = (size_t)l*DM;
    cvt(dec_Wk+wo, w0hi, w0lo, MM);
    cvt(dec_Wv+wo, w1hi, w1lo, MM);
    gemm_split<0,3><<<dim3(32,8),256,0,stream>>>(hshi, hslo, w0hi, w0lo, dec_bk+bo_,
        (float*)nullptr, kcb+(size_t)l*BT*DM, (short*)nullptr, BT, DM, DM);
    gemm_split<0,3><<<dim3(32,8),256,0,stream>>>(hshi, hslo, w1hi, w1lo, dec_bv+bo_,
        (float*)nullptr, vcb+(size_t)l*BT*DM, (short*)nullptr, BT, DM, DM);
  }

  // ---- decoder weight setup: combined Wqo + swizzled weights (once) ----
  // NOTE: wqoh/wqol alias wfhi/wflo (ffe_W1 split) — dead after encoder.
  for (int l=0; l<NL; ++l) {
    const size_t wo = (size_t)l*DM*DM, bo_ = (size_t)l*DM;
    // Wc = Wq @ Wo, bc = Wq@bo + bq
    k_transpose<<<1024, 256, 0, stream>>>(dec_Wo+wo, wotf);
    cvt(wotf,      w0hi, w0lo, MM);
    cvt(dec_Wq+wo, w1hi, w1lo, MM);
    gemm_split<0,0><<<dim3(8,8),256,0,stream>>>(w1hi, w1lo, w0hi, w0lo, zbuf,
        wcf, (short*)nullptr, (short*)nullptr, DM, DM, DM);
    k_bc<<<DM, 256, 0, stream>>>(dec_Wq+wo, dec_bo+bo_, dec_bq+bo_, bqo+bo_);
    swz(wcf,       wqoh + (size_t)l*MM, wqol + (size_t)l*MM, DM, DM);
    // direct weights (swizzled)
    swz(dec_Wq+wo, dwq + (size_t)l*2*MM, dwq + (size_t)l*2*MM + MM, DM, DM);
    swz(dec_Wk+wo, dwk + (size_t)l*2*MM, dwk + (size_t)l*2*MM + MM, DM, DM);
    swz(dec_Wv+wo, dwv + (size_t)l*2*MM, dwv + (size_t)l*2*MM + MM, DM, DM);
    swz(dec_Wo+wo, dwo + (size_t)l*2*MM, dwo + (size_t)l*2*MM + MM, DM, DM);
  }
  swz(ffd_W1, fw1h, fw1l, DFFN, DM);
  swz(ffd_W2, fw2h, fw2l, DM, DFFN);

  // ---- decoder: 8 kernels/layer ----
  k_init0<<<BB, 256, 0, stream>>>(dphi, dplo);
  for (int s=0; s<NSTEP; ++s){
    const int n = s+1, rows = 4*n;
    const int mr = (rows + 15) >> 4;
    for (int l=0; l<NL; ++l){
      const short* qh = dwq + (size_t)l*2*MM; const short* ql = qh + MM;
      const short* kh = dwk + (size_t)l*2*MM; const short* kl = kh + MM;
      const short* vh = dwv + (size_t)l*2*MM; const short* vl = vh + MM;
      const short* oh = dwo + (size_t)l*2*MM; const short* ol = oh + MM;
      const float* lbq = dec_bq + (size_t)l*DM;
      const float* lbk = dec_bk + (size_t)l*DM;
      const float* lbv = dec_bv + (size_t)l*DM;
      const float* lbo = dec_bo + (size_t)l*DM;
      const short* in_hi = (l==0) ? dphi : dlhi;
      const short* in_lo = (l==0) ? dplo : dllo;
      k_fattn<<<64, 256, 0, stream>>>(in_hi, in_lo, qh,ql, kh,kl, vh,vl,
          lbq, lbk, lbv, dahi, dalo, n);
      k_proj<1><<<64, 256, 0, stream>>>(dahi, dalo,
          wqoh + (size_t)l*MM, wqol + (size_t)l*MM, bqo + (size_t)l*DM,
          dq, (short*)nullptr, (short*)nullptr, mr);
      k_cross_part<<<dim3(CSPLIT, 64), 256, 0, stream>>>(dq,
          kcb + (size_t)l*BT*DM, vcb + (size_t)l*BT*DM, opart, mlp, n);
      k_comb<<<64, 256, 0, stream>>>(opart, mlp, dahi, dalo, n);
      k_proj<3><<<64, 256, 0, stream>>>(dahi, dalo, oh, ol, lbo,
          dbuf, dxhi, dxlo, mr);
      k_ffn1<<<256, 256, 0, stream>>>(dxhi, dxlo, fw1h, fw1l, ffd_b1,
          dmhi, dmlo, mr);
      k_ffn2<<<dim3(64,2), 256, 0, stream>>>(dmhi, dmlo, fw2h, fw2l, part, mr);
      k_ln<<<rows, 256, 0, stream>>>(part, ffd_b2, dbuf, nd_g, nd_b,
          dbuf, dlhi, dllo);
    }
    k_out<<<BB, 256, 0, stream>>>(dbuf, out_W, out_b, temb_W, temb_b, dout,
        dphi, dplo, s);
  }
}

// Round 12
// 13603.384 us; speedup vs baseline: 1.6350x; 1.6350x over previous
//
#include <hip/hip_runtime.h>
#include <math.h>

#define DM    1024
#define NH    16
#define DKH   64
#define NL    4
#define DFFN  4096
#define BB    4
#define TT    1024
#define NSTEP 24
#define BT    (BB*TT)      // 4096 encoder rows
#define MD    (BB*NSTEP)   // 96 decoder rows max (packed: row = i*4 + b)
#define CSPLIT 8
#define CKEYS  (TT/CSPLIT) // 128 keys per cross-attn split
#define PSTRIDE ((size_t)MD*DM)        // partial stride (f32)

typedef __attribute__((ext_vector_type(8))) short s16x8;
typedef __attribute__((ext_vector_type(4))) short s16x4;
typedef __attribute__((ext_vector_type(4))) float f32x4;

__device__ inline short f2b(float f){
  unsigned u = __float_as_uint(f);
  u += 0x7fffu + ((u>>16)&1u);          // round-to-nearest-even
  return (short)(u>>16);
}
__device__ inline float b2f(short h){
  return __uint_as_float(((unsigned)(unsigned short)h)<<16);
}

__device__ inline float wave_sum(float v){
  #pragma unroll
  for (int off=1; off<64; off<<=1) v += __shfl_xor(v, off, 64);
  return v;
}

// ---------------- f32 -> (hi,lo) bf16 split ----------------
__global__ __launch_bounds__(256)
void split_kernel(const float* __restrict__ X, short* __restrict__ Hi,
                  short* __restrict__ Lo, int n8)
{
  const size_t i = (size_t)blockIdx.x*256 + threadIdx.x;
  if (i >= (size_t)n8) return;
  const float4 v0 = *(const float4*)(X + i*8);
  const float4 v1 = *(const float4*)(X + i*8 + 4);
  const float f[8] = {v0.x,v0.y,v0.z,v0.w,v1.x,v1.y,v1.z,v1.w};
  s16x8 hv, lv;
  #pragma unroll
  for (int e=0;e<8;e++){
    const short h = f2b(f[e]);
    hv[e] = h;
    lv[e] = f2b(f[e] - b2f(h));
  }
  *(s16x8*)(Hi + i*8) = hv;
  *(s16x8*)(Lo + i*8) = lv;
}

__global__ void zero_kernel(float* __restrict__ p, int n) {
  int i = blockIdx.x*256 + threadIdx.x;
  if (i < n) p[i] = 0.f;
}

// f32 1024x1024 transpose
__global__ __launch_bounds__(256)
void k_transpose(const float* __restrict__ A, float* __restrict__ At)
{
  __shared__ float tile[32][33];
  const int bx = blockIdx.x & 31, by = blockIdx.x >> 5;
  const int x0 = bx*32, y0 = by*32;
  const int tid = threadIdx.x;
  for (int i=tid; i<1024; i+=256){
    const int r = i>>5, c = i&31;
    tile[r][c] = A[(size_t)(y0+r)*DM + x0+c];
  }
  __syncthreads();
  for (int i=tid; i<1024; i+=256){
    const int r = i>>5, c = i&31;
    At[(size_t)(x0+r)*DM + y0+c] = tile[c][r];
  }
}

// bc[row] = dot(Wq[row,:], bo) + bq[row]
__global__ __launch_bounds__(256)
void k_bc(const float* __restrict__ Wq, const float* __restrict__ bo,
          const float* __restrict__ bq, float* __restrict__ bc)
{
  const int row = blockIdx.x, tid = threadIdx.x;
  float s = 0.f;
  for (int j=tid; j<DM; j+=256) s += Wq[(size_t)row*DM + j]*bo[j];
  s = wave_sum(s);
  __shared__ float r4[4];
  if ((tid&63)==0) r4[tid>>6] = s;
  __syncthreads();
  if (tid==0) bc[row] = r4[0]+r4[1]+r4[2]+r4[3] + bq[row];
}

// h[row] + pe[row%TT] -> split bf16 (encoder)
__global__ __launch_bounds__(256)
void add_pe_split(const float* __restrict__ h, short* __restrict__ Hi,
                  short* __restrict__ Lo)
{
  const int row = blockIdx.x;
  const int pos = row & (TT-1);
  const int d = threadIdx.x*4;
  const float4 a = *(const float4*)(h + (size_t)row*DM + d);
  const float c1 = -9.210340371976184f / 1024.0f;
  const float e0 = expf((float)d * c1);
  const float e1 = expf((float)(d+2) * c1);
  const float a0 = (float)pos * e0, a1 = (float)pos * e1;
  const float v[4] = {a.x + sinf(a0), a.y + cosf(a0), a.z + sinf(a1), a.w + cosf(a1)};
  s16x4 hv, lv;
  #pragma unroll
  for (int e=0;e<4;e++){
    const short hb = f2b(v[e]);
    hv[e] = hb;
    lv[e] = f2b(v[e] - b2f(hb));
  }
  *(s16x4*)(Hi + (size_t)row*DM + d) = hv;
  *(s16x4*)(Lo + (size_t)row*DM + d) = lv;
}

// ---------------- split-bf16 MFMA GEMM (encoder/setup): C = A @ W^T + bias ------
// OUT_MODE: 0 f32; 1 split; 2 both; 3 plain-bf16 Chi.
template<int ACT, int OUT_MODE>
__global__ __launch_bounds__(256, 2)
void gemm_split(const short* __restrict__ Ahi, const short* __restrict__ Alo,
                const short* __restrict__ Bhi, const short* __restrict__ Blo,
                const float* __restrict__ bias,
                float* __restrict__ C, short* __restrict__ Chi, short* __restrict__ Clo,
                int M, int N, int K)
{
  __shared__ __align__(16) short lA[2][128][40];
  __shared__ __align__(16) short lB[2][128][40];
  const int tid = threadIdx.x;
  const int m0 = blockIdx.x*128, n0 = blockIdx.y*128;
  const int lane = tid & 63, w = tid >> 6;
  const int wr = w >> 1, wc = w & 1;
  const int fr = lane & 15, fq = lane >> 4;

  f32x4 acc[4][4];
  #pragma unroll
  for (int i=0;i<4;i++)
    #pragma unroll
    for (int j=0;j<4;j++) acc[i][j] = (f32x4){0.f,0.f,0.f,0.f};

  for (int k0 = 0; k0 < K; k0 += 32) {
    __syncthreads();
    #pragma unroll
    for (int j=0;j<2;j++){
      const int cc = tid + j*256;
      const int row = cc >> 2, kq = cc & 3;
      const size_t ga = (size_t)(m0+row)*K + k0 + kq*8;
      const size_t gb = (size_t)(n0+row)*K + k0 + kq*8;
      *(s16x8*)&lA[0][row][kq*8] = *(const s16x8*)(Ahi + ga);
      *(s16x8*)&lA[1][row][kq*8] = *(const s16x8*)(Alo + ga);
      *(s16x8*)&lB[0][row][kq*8] = *(const s16x8*)(Bhi + gb);
      *(s16x8*)&lB[1][row][kq*8] = *(const s16x8*)(Blo + gb);
    }
    __syncthreads();
    s16x8 ah[4], al[4], bh[4], bl[4];
    #pragma unroll
    for (int i=0;i<4;i++){
      ah[i] = *(const s16x8*)&lA[0][wr*64+i*16+fr][fq*8];
      al[i] = *(const s16x8*)&lA[1][wr*64+i*16+fr][fq*8];
    }
    #pragma unroll
    for (int j=0;j<4;j++){
      bh[j] = *(const s16x8*)&lB[0][wc*64+j*16+fr][fq*8];
      bl[j] = *(const s16x8*)&lB[1][wc*64+j*16+fr][fq*8];
    }
    #pragma unroll
    for (int i=0;i<4;i++)
      #pragma unroll
      for (int j=0;j<4;j++){
        acc[i][j] = __builtin_amdgcn_mfma_f32_16x16x32_bf16(ah[i], bh[j], acc[i][j], 0,0,0);
        acc[i][j] = __builtin_amdgcn_mfma_f32_16x16x32_bf16(ah[i], bl[j], acc[i][j], 0,0,0);
        acc[i][j] = __builtin_amdgcn_mfma_f32_16x16x32_bf16(al[i], bh[j], acc[i][j], 0,0,0);
      }
  }
  #pragma unroll
  for (int j=0;j<4;j++){
    const int col = n0 + wc*64 + j*16 + fr;
    const float bv = bias[col];
    #pragma unroll
    for (int i=0;i<4;i++){
      const int row0 = m0 + wr*64 + i*16 + fq*4;
      #pragma unroll
      for (int r=0;r<4;r++){
        float v = acc[i][j][r] + bv;
        if (ACT==1) v = fmaxf(v, 0.f);
        const size_t idx = (size_t)(row0+r)*N + col;
        if (OUT_MODE==0 || OUT_MODE==2) C[idx] = v;
        if (OUT_MODE==1 || OUT_MODE==2){
          const short hb = f2b(v);
          Chi[idx] = hb;
          Clo[idx] = f2b(v - b2f(hb));
        }
        if (OUT_MODE==3) Chi[idx] = f2b(v);
      }
    }
  }
}

// ---------------- encoder self-attention (flash, thread-per-q-row, split out) ----
__global__ __launch_bounds__(256)
void attn_enc(const float* __restrict__ Qg, const float* __restrict__ Kg,
              const float* __restrict__ Vg, short* __restrict__ Ohi,
              short* __restrict__ Olo)
{
  const int bh = blockIdx.y;
  const int b = bh >> 4, hh = bh & 15;
  const int row = blockIdx.x*256 + threadIdx.x;
  const size_t base = ((size_t)b*TT)*DM + hh*DKH;
  float q[64];
  {
    const float* qp = Qg + base + (size_t)row*DM;
    #pragma unroll
    for (int d4=0; d4<16; d4++){
      const float4 v = *(const float4*)(qp + d4*4);
      q[d4*4+0]=v.x; q[d4*4+1]=v.y; q[d4*4+2]=v.z; q[d4*4+3]=v.w;
    }
  }
  float o[64];
  #pragma unroll
  for (int d=0;d<64;d++) o[d]=0.f;
  float m = -INFINITY, l = 0.f;
  __shared__ float Ks[64][68];
  __shared__ float Vs[64][68];
  for (int kt=0; kt<TT; kt+=64) {
    __syncthreads();
    #pragma unroll
    for (int t=0;t<4;t++){
      const int fi = threadIdx.x + t*256;
      const int j = fi>>4, dq = fi&15;
      *(float4*)&Ks[j][dq*4] = *(const float4*)(Kg + base + (size_t)(kt+j)*DM + dq*4);
      *(float4*)&Vs[j][dq*4] = *(const float4*)(Vg + base + (size_t)(kt+j)*DM + dq*4);
    }
    __syncthreads();
    for (int j=0;j<64;j++){
      float s0=0.f,s1=0.f,s2=0.f,s3=0.f;
      #pragma unroll
      for (int d=0; d<64; d+=4){
        s0 = fmaf(q[d+0], Ks[j][d+0], s0);
        s1 = fmaf(q[d+1], Ks[j][d+1], s1);
        s2 = fmaf(q[d+2], Ks[j][d+2], s2);
        s3 = fmaf(q[d+3], Ks[j][d+3], s3);
      }
      const float s = ((s0+s1)+(s2+s3)) * 0.125f;
      if (s > m) {
        const float f = __expf(m - s);
        l *= f;
        #pragma unroll
        for (int d=0;d<64;d++) o[d] *= f;
        m = s;
      }
      const float p = __expf(s - m);
      l += p;
      #pragma unroll
      for (int d=0;d<64;d++) o[d] = fmaf(p, Vs[j][d], o[d]);
    }
  }
  const float inv = 1.f / l;
  #pragma unroll
  for (int d8=0; d8<8; d8++){
    s16x8 hv, lv;
    #pragma unroll
    for (int e=0;e<8;e++){
      const float f = o[d8*8+e]*inv;
      const short hb = f2b(f);
      hv[e] = hb;
      lv[e] = f2b(f - b2f(hb));
    }
    *(s16x8*)(Ohi + base + (size_t)row*DM + d8*8) = hv;
    *(s16x8*)(Olo + base + (size_t)row*DM + d8*8) = lv;
  }
}

// encoder LayerNorm: split bf16 out
__global__ __launch_bounds__(256)
void ln_add_split(const float* __restrict__ X, const float* __restrict__ Y,
                  const float* __restrict__ g, const float* __restrict__ be,
                  short* __restrict__ Ohi, short* __restrict__ Olo)
{
  const size_t row = blockIdx.x;
  const int tid = threadIdx.x;
  const float4 a = *(const float4*)(X + row*DM + tid*4);
  const float4 b = *(const float4*)(Y + row*DM + tid*4);
  const float v0=a.x+b.x, v1=a.y+b.y, v2=a.z+b.z, v3=a.w+b.w;
  float s = v0+v1+v2+v3;
  float q = v0*v0+v1*v1+v2*v2+v3*v3;
  s = wave_sum(s); q = wave_sum(q);
  __shared__ float rs[4], rq[4];
  if ((tid&63)==0){ rs[tid>>6]=s; rq[tid>>6]=q; }
  __syncthreads();
  const float S = rs[0]+rs[1]+rs[2]+rs[3];
  const float Q = rq[0]+rq[1]+rq[2]+rq[3];
  const float mean = S * (1.f/DM);
  const float var  = Q * (1.f/DM) - mean*mean;
  const float rstd = rsqrtf(var + 1e-5f);
  const float4 gv = *(const float4*)(g  + tid*4);
  const float4 bv = *(const float4*)(be + tid*4);
  const float v[4] = {(v0-mean)*rstd*gv.x + bv.x, (v1-mean)*rstd*gv.y + bv.y,
                      (v2-mean)*rstd*gv.z + bv.z, (v3-mean)*rstd*gv.w + bv.w};
  s16x4 hv, lv;
  #pragma unroll
  for (int e=0;e<4;e++){
    const short hb = f2b(v[e]);
    hv[e] = hb;
    lv[e] = f2b(v[e] - b2f(hb));
  }
  *(s16x4*)(Ohi + row*DM + tid*4) = hv;
  *(s16x4*)(Olo + row*DM + tid*4) = lv;
}

// ================= decoder (r4 engine: LDS-staged split-MFMA, K-split partials) ==

// A[Mt x K] split bf16 (packed rows), W[N x K]^T split bf16 (3 selectable),
// partials P[z][ks][MD][N] f32. Tile: Mt x 128, 4 waves (32 cols each).
template<int MR>
__global__ __launch_bounds__(256)
void gemm_dec(const short* __restrict__ Ahi, const short* __restrict__ Alo,
              const short* __restrict__ B0hi, const short* __restrict__ B0lo,
              const short* __restrict__ B1hi, const short* __restrict__ B1lo,
              const short* __restrict__ B2hi, const short* __restrict__ B2lo,
              float* __restrict__ part, int N, int K, int KS)
{
  const short* Bhi = (blockIdx.z==0) ? B0hi : (blockIdx.z==1 ? B1hi : B2hi);
  const short* Blo = (blockIdx.z==0) ? B0lo : (blockIdx.z==1 ? B1lo : B2lo);
  float* P = part + ((size_t)blockIdx.z*KS + blockIdx.y)*(size_t)MD*N;
  const int KK = K / KS;
  const int kbase = blockIdx.y * KK;
  const int n0 = blockIdx.x * 128;
  __shared__ __align__(16) short lA[2][96][40];
  __shared__ __align__(16) short lB[2][128][40];
  const int tid = threadIdx.x;
  const int lane = tid & 63, w = tid >> 6;
  const int fr = lane & 15, fq = lane >> 4;
  constexpr int CH = MR*128;                 // A staging chunks (Mt rows x 8)

  f32x4 acc[MR][2];
  #pragma unroll
  for (int i=0;i<MR;i++){ acc[i][0]=(f32x4){0,0,0,0}; acc[i][1]=(f32x4){0,0,0,0}; }

  for (int k0 = kbase; k0 < kbase + KK; k0 += 32) {
    __syncthreads();
    #pragma unroll
    for (int t=0; t<(CH+255)/256; t++){
      const int cc = tid + t*256;
      if (cc < CH){
        const int row = cc>>3, hl = (cc>>2)&1, kq = cc&3;
        const short* src = hl ? Alo : Ahi;
        *(s16x8*)&lA[hl][row][kq*8] = *(const s16x8*)(src + (size_t)row*K + k0 + kq*8);
      }
    }
    #pragma unroll
    for (int t=0; t<4; t++){
      const int cc = tid + t*256;
      const int row = cc>>3, hl = (cc>>2)&1, kq = cc&3;
      const short* src = hl ? Blo : Bhi;
      *(s16x8*)&lB[hl][row][kq*8] = *(const s16x8*)(src + (size_t)(n0+row)*K + k0 + kq*8);
    }
    __syncthreads();
    s16x8 bh[2], bl[2];
    #pragma unroll
    for (int j=0;j<2;j++){
      bh[j] = *(const s16x8*)&lB[0][w*32+j*16+fr][fq*8];
      bl[j] = *(const s16x8*)&lB[1][w*32+j*16+fr][fq*8];
    }
    #pragma unroll
    for (int i=0;i<MR;i++){
      const s16x8 ah = *(const s16x8*)&lA[0][i*16+fr][fq*8];
      const s16x8 al = *(const s16x8*)&lA[1][i*16+fr][fq*8];
      #pragma unroll
      for (int j=0;j<2;j++){
        acc[i][j] = __builtin_amdgcn_mfma_f32_16x16x32_bf16(ah, bh[j], acc[i][j], 0,0,0);
        acc[i][j] = __builtin_amdgcn_mfma_f32_16x16x32_bf16(ah, bl[j], acc[i][j], 0,0,0);
        acc[i][j] = __builtin_amdgcn_mfma_f32_16x16x32_bf16(al, bh[j], acc[i][j], 0,0,0);
      }
    }
  }
  #pragma unroll
  for (int j=0;j<2;j++){
    const int col = n0 + w*32 + j*16 + fr;
    #pragma unroll
    for (int i=0;i<MR;i++){
      const int row0 = i*16 + fq*4;
      #pragma unroll
      for (int r=0;r<4;r++)
        P[(size_t)(row0+r)*N + col] = acc[i][j][r];
    }
  }
}

// reduce partials + bias (+ReLU); MODE: 0=f32, 1=split, 2=both (split for z==0)
template<int ACT, int MODE>
__global__ __launch_bounds__(256)
void reduce_dec(const float* __restrict__ part,
                const float* __restrict__ b0, const float* __restrict__ b1,
                const float* __restrict__ b2,
                float* __restrict__ o0, float* __restrict__ o1, float* __restrict__ o2,
                short* __restrict__ ohi, short* __restrict__ olo,
                int N, int KS)
{
  const int idx = blockIdx.x*256 + threadIdx.x;
  const int z = blockIdx.y;
  const float* P = part + (size_t)z*KS*(size_t)MD*N;
  const float* bias = (z==0)?b0:(z==1?b1:b2);
  float* out = (z==0)?o0:(z==1?o1:o2);
  float s = 0.f;
  for (int ks=0; ks<KS; ks++) s += P[(size_t)ks*MD*N + idx];
  s += bias[idx & (N-1)];
  if (ACT==1) s = fmaxf(s, 0.f);
  if (MODE==0 || MODE==2) out[idx] = s;
  if (MODE==1 || MODE==2){
    if (z==0){
      const short hb = f2b(s);
      ohi[idx] = hb;
      olo[idx] = f2b(s - b2f(hb));
    }
  }
}

// self-attention with inline QKV partial-reduce (KS=8, layout [3][8][MD][DM]).
// 64 blocks = (b,hh). Split out.
__global__ __launch_bounds__(256)
void attn_qkv(const float* __restrict__ part,
              const float* __restrict__ lbq, const float* __restrict__ lbk,
              const float* __restrict__ lbv,
              short* __restrict__ Ohi, short* __restrict__ Olo, int n)
{
  const int bh = blockIdx.x, b = bh >> 4, hh = bh & 15;
  const size_t obase = (size_t)b*DM + hh*DKH;
  __shared__ float Qs[NSTEP][68], Ks[NSTEP][68], Vs[NSTEP][68];
  __shared__ float P[NSTEP][28];
  const int tid = threadIdx.x;
  for (int t = tid; t < 3*n*16; t += 256){
    const int tensor = t / (n*16);
    const int fi = t - tensor*(n*16);
    const int row = fi >> 4, q4 = fi & 15;
    const int col0 = hh*DKH + q4*4;
    const float* bias = (tensor==0?lbq:(tensor==1?lbk:lbv));
    float4 a;
    a.x = bias[col0]; a.y = bias[col0+1]; a.z = bias[col0+2]; a.w = bias[col0+3];
    const size_t eoff = (size_t)(row*4+b)*DM + col0;
    #pragma unroll
    for (int ks=0; ks<8; ks++){
      const float4 p = *(const float4*)(part + (size_t)(tensor*8+ks)*PSTRIDE + eoff);
      a.x+=p.x; a.y+=p.y; a.z+=p.z; a.w+=p.w;
    }
    float (*dst)[68] = (tensor==0?Qs:(tensor==1?Ks:Vs));
    *(float4*)&dst[row][q4*4] = a;
  }
  __syncthreads();
  for (int idx = tid; idx < n*n; idx += 256){
    const int i = idx / n, j = idx - i*n;
    float s0=0.f,s1=0.f,s2=0.f,s3=0.f;
    #pragma unroll
    for (int d=0; d<64; d+=4){
      s0 = fmaf(Qs[i][d+0], Ks[j][d+0], s0);
      s1 = fmaf(Qs[i][d+1], Ks[j][d+1], s1);
      s2 = fmaf(Qs[i][d+2], Ks[j][d+2], s2);
      s3 = fmaf(Qs[i][d+3], Ks[j][d+3], s3);
    }
    P[i][j] = ((s0+s1)+(s2+s3))*0.125f;
  }
  __syncthreads();
  if (tid < n){
    float mm = -INFINITY;
    for (int j=0;j<n;j++) mm = fmaxf(mm, P[tid][j]);
    float l = 0.f;
    for (int j=0;j<n;j++){ const float p = __expf(P[tid][j]-mm); P[tid][j]=p; l+=p; }
    const float inv = 1.f/l;
    for (int j=0;j<n;j++) P[tid][j] *= inv;
  }
  __syncthreads();
  for (int idx = tid; idx < n*64; idx += 256){
    const int i = idx >> 6, d = idx & 63;
    float s = 0.f;
    for (int j=0;j<n;j++) s = fmaf(P[i][j], Vs[j][d], s);
    const short hb = f2b(s);
    const size_t o = obase + (size_t)(i*4)*DM + d;
    Ohi[o] = hb;
    Olo[o] = f2b(s - b2f(hb));
  }
}

// cross-attn partials: grid (CSPLIT, 64)
__global__ __launch_bounds__(256)
void attn_cross_part(const float* __restrict__ Qg, const short* __restrict__ Kc,
                     const short* __restrict__ Vc, float* __restrict__ opart,
                     float* __restrict__ mlpart, int n)
{
  const int ks = blockIdx.x, bh = blockIdx.y;
  const int b = bh >> 4, hh = bh & 15;
  __shared__ float Qs[NSTEP][68];
  __shared__ short KVs[CKEYS][72];
  __shared__ float S[NSTEP][132];
  const int tid = threadIdx.x;
  const size_t qbase = (size_t)b*DM + hh*DKH;
  for (int t=tid; t<n*16; t+=256){
    const int row = t>>4, q4 = t&15;
    *(float4*)&Qs[row][q4*4] = *(const float4*)(Qg + qbase + (size_t)(row*4)*DM + q4*4);
  }
  const size_t kbase = ((size_t)b*TT + (size_t)ks*CKEYS)*DM + hh*DKH;
  for (int t=tid; t<CKEYS*8; t+=256){
    const int row = t>>3, d8 = t&7;
    *(s16x8*)&KVs[row][d8*8] = *(const s16x8*)(Kc + kbase + (size_t)row*DM + d8*8);
  }
  __syncthreads();
  for (int idx=tid; idx<n*128; idx+=256){
    const int i = idx >> 7, j = idx & 127;
    float s0=0.f,s1=0.f,s2=0.f,s3=0.f;
    #pragma unroll
    for (int d=0; d<64; d+=4){
      s0 = fmaf(Qs[i][d+0], b2f(KVs[j][d+0]), s0);
      s1 = fmaf(Qs[i][d+1], b2f(KVs[j][d+1]), s1);
      s2 = fmaf(Qs[i][d+2], b2f(KVs[j][d+2]), s2);
      s3 = fmaf(Qs[i][d+3], b2f(KVs[j][d+3]), s3);
    }
    S[i][j] = ((s0+s1)+(s2+s3))*0.125f;
  }
  __syncthreads();
  for (int t=tid; t<CKEYS*8; t+=256){         // V over K buffer
    const int row = t>>3, d8 = t&7;
    *(s16x8*)&KVs[row][d8*8] = *(const s16x8*)(Vc + kbase + (size_t)row*DM + d8*8);
  }
  if (tid < n){
    float mm=-INFINITY;
    for (int j=0;j<CKEYS;j++) mm = fmaxf(mm, S[tid][j]);
    float l=0.f;
    for (int j=0;j<CKEYS;j++){ const float p=__expf(S[tid][j]-mm); S[tid][j]=p; l+=p; }
    mlpart[((size_t)bh*CSPLIT+ks)*(2*NSTEP) + tid*2+0] = mm;
    mlpart[((size_t)bh*CSPLIT+ks)*(2*NSTEP) + tid*2+1] = l;
  }
  __syncthreads();
  for (int idx=tid; idx<n*64; idx+=256){
    const int i = idx >> 6, d = idx & 63;
    float s=0.f;
    for (int j=0;j<CKEYS;j++) s = fmaf(S[i][j], b2f(KVs[j][d]), s);
    opart[(((size_t)bh*CSPLIT+ks)*NSTEP + i)*DKH + d] = s;
  }
}

__global__ __launch_bounds__(256)
void attn_cross_comb(const float* __restrict__ opart, const float* __restrict__ mlpart,
                     short* __restrict__ Ohi, short* __restrict__ Olo, int n)
{
  const int bh = blockIdx.x;
  const int idx = blockIdx.y*256 + threadIdx.x;
  const int i = idx >> 6, d = idx & 63;
  if (i >= n) return;
  float M = -INFINITY;
  #pragma unroll
  for (int s=0;s<CSPLIT;s++)
    M = fmaxf(M, mlpart[((size_t)bh*CSPLIT+s)*(2*NSTEP) + i*2]);
  float acc = 0.f, L = 0.f;
  #pragma unroll
  for (int s=0;s<CSPLIT;s++){
    const float mm = mlpart[((size_t)bh*CSPLIT+s)*(2*NSTEP) + i*2+0];
    const float ll = mlpart[((size_t)bh*CSPLIT+s)*(2*NSTEP) + i*2+1];
    const float f = __expf(mm - M);
    acc = fmaf(f, opart[(((size_t)bh*CSPLIT+s)*NSTEP + i)*DKH + d], acc);
    L   = fmaf(f, ll, L);
  }
  const int b = bh >> 4, hh = bh & 15;
  const float v = acc / L;
  const short hb = f2b(v);
  const size_t o = ((size_t)(i*4+b))*DM + hh*DKH + d;
  Ohi[o] = hb;
  Olo[o] = f2b(v - b2f(hb));
}

// reduce FFN2 partials(16) + bias + residual -> LN -> dbuf f32 + split. rows blocks.
__global__ __launch_bounds__(256)
void k_lnr(const float* __restrict__ part, const float* __restrict__ bias,
           const float* __restrict__ X, const float* __restrict__ g,
           const float* __restrict__ be,
           float* __restrict__ Outf, short* __restrict__ Ohi, short* __restrict__ Olo)
{
  const int row = blockIdx.x;
  __shared__ float rs[4], rq[4];
  const int tid = threadIdx.x;
  float a0=0.f,a1=0.f,a2=0.f,a3=0.f;
  #pragma unroll
  for (int ks=0; ks<16; ks++){
    const float4 p = *(const float4*)(part + (size_t)ks*PSTRIDE + (size_t)row*DM + tid*4);
    a0+=p.x; a1+=p.y; a2+=p.z; a3+=p.w;
  }
  const float4 bvv = *(const float4*)(bias + tid*4);
  const float4 xv  = *(const float4*)(X + (size_t)row*DM + tid*4);
  const float v0=a0+bvv.x+xv.x, v1=a1+bvv.y+xv.y, v2=a2+bvv.z+xv.z, v3=a3+bvv.w+xv.w;
  float s = v0+v1+v2+v3;
  float q = v0*v0+v1*v1+v2*v2+v3*v3;
  s = wave_sum(s); q = wave_sum(q);
  if ((tid&63)==0){ rs[tid>>6]=s; rq[tid>>6]=q; }
  __syncthreads();
  const float S = rs[0]+rs[1]+rs[2]+rs[3];
  const float Q = rq[0]+rq[1]+rq[2]+rq[3];
  const float mean = S * (1.f/DM);
  const float var  = Q * (1.f/DM) - mean*mean;
  const float rstd = rsqrtf(var + 1e-5f);
  const float4 gv = *(const float4*)(g  + tid*4);
  const float4 bv2 = *(const float4*)(be + tid*4);
  const float v[4] = {(v0-mean)*rstd*gv.x + bv2.x, (v1-mean)*rstd*gv.y + bv2.y,
                      (v2-mean)*rstd*gv.z + bv2.z, (v3-mean)*rstd*gv.w + bv2.w};
  float4 of; of.x=v[0]; of.y=v[1]; of.z=v[2]; of.w=v[3];
  *(float4*)(Outf + (size_t)row*DM + tid*4) = of;
  s16x4 hv, lv;
  #pragma unroll
  for (int e=0;e<4;e++){
    const short hb = f2b(v[e]);
    hv[e] = hb;
    lv[e] = f2b(v[e] - b2f(hb));
  }
  *(s16x4*)(Ohi + (size_t)row*DM + tid*4) = hv;
  *(s16x4*)(Olo + (size_t)row*DM + tid*4) = lv;
}

// final projection + write next step's split input (emb + PE). 4 blocks.
__global__ __launch_bounds__(256)
void k_out(const float* __restrict__ Dv, const float* __restrict__ outW,
           const float* __restrict__ outB, const float* __restrict__ tembW,
           const float* __restrict__ tembB, float* __restrict__ dout,
           short* __restrict__ Dphi, short* __restrict__ Dplo, int s)
{
  const int b = blockIdx.x;
  __shared__ float red[4];
  __shared__ float stepv;
  const int tid = threadIdx.x;
  const float* drow = Dv + ((size_t)(s*4 + b))*DM;
  const float4 dv4 = *(const float4*)(drow + tid*4);
  const float4 wv = *(const float4*)(outW + tid*4);
  float p = dv4.x*wv.x + dv4.y*wv.y + dv4.z*wv.z + dv4.w*wv.w;
  p = wave_sum(p);
  if ((tid&63)==0) red[tid>>6] = p;
  __syncthreads();
  if (tid==0){
    const float sv = red[0]+red[1]+red[2]+red[3] + outB[0];
    stepv = sv;
    dout[b*NSTEP + s] = sv;
  }
  __syncthreads();
  const float sv = stepv;
  if (s+1 < NSTEP){
    const int d = tid*4, pos = s+1;
    const float4 tw = *(const float4*)(tembW + d);
    const float4 tb = *(const float4*)(tembB + d);
    const float c1 = -9.210340371976184f / 1024.0f;
    const float e0 = expf((float)d * c1);
    const float e1 = expf((float)(d+2) * c1);
    const float a0 = (float)pos * e0, a1 = (float)pos * e1;
    const float v[4] = { fmaf(sv, tw.x, tb.x) + sinf(a0),
                         fmaf(sv, tw.y, tb.y) + cosf(a0),
                         fmaf(sv, tw.z, tb.z) + sinf(a1),
                         fmaf(sv, tw.w, tb.w) + cosf(a1) };
    s16x4 hv, lv;
    #pragma unroll
    for (int e=0;e<4;e++){
      const short hb = f2b(v[e]);
      hv[e] = hb;
      lv[e] = f2b(v[e] - b2f(hb));
    }
    const size_t o = (size_t)(pos*4 + b)*DM + d;
    *(s16x4*)(Dphi + o) = hv;
    *(s16x4*)(Dplo + o) = lv;
  }
}

// step-0 input rows: split(0 + pe[0])
__global__ __launch_bounds__(256)
void k_init0(short* __restrict__ Dphi, short* __restrict__ Dplo)
{
  const int b = blockIdx.x;
  const int d = threadIdx.x*4;
  const float v[4] = {0.f, 1.f, 0.f, 1.f};   // sin(0), cos(0)
  s16x4 hv, lv;
  #pragma unroll
  for (int e=0;e<4;e++){
    const short hb = f2b(v[e]);
    hv[e] = hb;
    lv[e] = f2b(v[e] - b2f(hb));
  }
  *(s16x4*)(Dphi + (size_t)b*DM + d) = hv;
  *(s16x4*)(Dplo + (size_t)b*DM + d) = lv;
}

// ---------------- orchestration ----------------
extern "C" void kernel_launch(void* const* d_in, const int* in_sizes, int n_in,
                              void* d_out, int out_size, void* d_ws, size_t ws_size,
                              hipStream_t stream)
{
  (void)in_sizes; (void)n_in; (void)out_size; (void)ws_size;
  const float* x      = (const float*)d_in[0];
  const float* in_W   = (const float*)d_in[1];
  const float* in_b   = (const float*)d_in[2];
  const float* enc_Wq = (const float*)d_in[3];
  const float* enc_bq = (const float*)d_in[4];
  const float* enc_Wk = (const float*)d_in[5];
  const float* enc_bk = (const float*)d_in[6];
  const float* enc_Wv = (const float*)d_in[7];
  const float* enc_bv = (const float*)d_in[8];
  const float* enc_Wo = (const float*)d_in[9];
  const float* enc_bo = (const float*)d_in[10];
  const float* dec_Wq = (const float*)d_in[11];
  const float* dec_bq = (const float*)d_in[12];
  const float* dec_Wk = (const float*)d_in[13];
  const float* dec_bk = (const float*)d_in[14];
  const float* dec_Wv = (const float*)d_in[15];
  const float* dec_bv = (const float*)d_in[16];
  const float* dec_Wo = (const float*)d_in[17];
  const float* dec_bo = (const float*)d_in[18];
  const float* ffe_W1 = (const float*)d_in[19];
  const float* ffe_b1 = (const float*)d_in[20];
  const float* ffe_W2 = (const float*)d_in[21];
  const float* ffe_b2 = (const float*)d_in[22];
  const float* ffd_W1 = (const float*)d_in[23];
  const float* ffd_b1 = (const float*)d_in[24];
  const float* ffd_W2 = (const float*)d_in[25];
  const float* ffd_b2 = (const float*)d_in[26];
  const float* ne_g   = (const float*)d_in[27];
  const float* ne_b   = (const float*)d_in[28];
  const float* nd_g   = (const float*)d_in[29];
  const float* nd_b   = (const float*)d_in[30];
  const float* out_W  = (const float*)d_in[31];
  const float* out_b  = (const float*)d_in[32];
  const float* temb_W = (const float*)d_in[33];
  const float* temb_b = (const float*)d_in[34];
  float* dout = (float*)d_out;

  float* ws = (float*)d_ws;
  size_t off = 0;
  auto alloc  = [&](size_t n){ n = (n+3)&~(size_t)3; float* p = ws + off; off += n; return p; };
  auto allocS = [&](size_t n){ size_t nf = ((n+1)/2 + 3)&~(size_t)3; short* p = (short*)(ws + off); off += nf; return p; };

  // encoder activations
  short* hshi = allocS((size_t)BT*DM);          // also hosts Wc-hi after KV build
  short* hslo = allocS((size_t)BT*DM);          // also hosts Wc-lo
  float* h    = alloc((size_t)BT*DM);           // also hosts dwo (split) in decoder
  float* hn   = h;
  float* t0   = alloc((size_t)BT*DM);           // also hosts dwq
  float* t1   = alloc((size_t)BT*DM);           // also hosts dwk
  float* t2   = alloc((size_t)BT*DM);           // also hosts dwv
  short* t3hi = allocS((size_t)BT*DM);          // also fw1h
  short* t3lo = allocS((size_t)BT*DM);          // also fw1l
  short* hnhi = allocS((size_t)BT*DM);          // also fw2h
  short* hnlo = allocS((size_t)BT*DM);          // also fw2l
  float* t4   = alloc((size_t)BT*DM);           // enc FFN2 out UNION setup temps UNION dec partials
  float* part = t4;
  short* fmhi = (short*)t0;                     // enc FFN hidden split (aliases t0..t3lo)
  short* fmlo = fmhi + (size_t)BT*DFFN;
  // bf16 K/V cross-attn cache
  short* kcb  = allocS((size_t)NL*BT*DM);
  short* vcb  = allocS((size_t)NL*BT*DM);
  // split inputs
  short* xshi = allocS((size_t)BT*64);
  short* xslo = allocS((size_t)BT*64);
  short* iwhi = allocS((size_t)DM*64);
  short* iwlo = allocS((size_t)DM*64);
  // per-layer reused weight slots (encoder + KV build + Wc setup)
  short* w0hi = allocS((size_t)DM*DM); short* w0lo = allocS((size_t)DM*DM);
  short* w1hi = allocS((size_t)DM*DM); short* w1lo = allocS((size_t)DM*DM);
  short* w2hi = allocS((size_t)DM*DM); short* w2lo = allocS((size_t)DM*DM);
  short* w3hi = allocS((size_t)DM*DM); short* w3lo = allocS((size_t)DM*DM);
  short* wfhi = allocS((size_t)DFFN*DM); short* wflo = allocS((size_t)DFFN*DM);   // ffe_W1 (hoisted)
  short* wf2hi= allocS((size_t)DM*DFFN); short* wf2lo= allocS((size_t)DM*DFFN);   // ffe_W2 (hoisted)
  float* bqo  = alloc((size_t)NL*DM);
  float* zbuf = alloc((size_t)DM);
  // decoder buffers (packed rows r = i*4+b)
  float* dq   = alloc((size_t)MD*DM);
  float* dbuf = alloc((size_t)MD*DM);
  short* dphi = allocS((size_t)MD*DM);  short* dplo = allocS((size_t)MD*DM);  // step input
  short* dlhi = allocS((size_t)MD*DM);  short* dllo = allocS((size_t)MD*DM);  // LN out
  short* dxhi = allocS((size_t)MD*DM);  short* dxlo = allocS((size_t)MD*DM);  // cross-O out
  short* dahi = allocS((size_t)MD*DM);  short* dalo = allocS((size_t)MD*DM);  // attn out (self & cross)
  short* dmhi = allocS((size_t)MD*DFFN);short* dmlo = allocS((size_t)MD*DFFN);
  float* opart= alloc((size_t)BB*NH*CSPLIT*NSTEP*DKH);
  float* mlp  = alloc((size_t)BB*NH*CSPLIT*2*NSTEP);

  // decoder split weights aliased onto dead-after-encoder buffers
  const size_t MM = (size_t)DM*DM;
  short* dwq = (short*)t0;
  short* dwk = (short*)t1;
  short* dwv = (short*)t2;
  short* dwo = (short*)h;
  short* fw1h = t3hi; short* fw1l = t3lo;
  short* fw2h = hnhi; short* fw2l = hnlo;
  short* wch  = hshi; short* wcl  = hslo;        // combined Wc = Wq@Wo (split, row-major)
  float* wotf = t4;                              // setup temp: Wo^T f32
  float* wcf  = t4 + MM;                         // setup temp: Wc f32

  auto cvt = [&](const float* src, short* hi, short* lo, size_t n){
    split_kernel<<<(int)((n/8 + 255)/256), 256, 0, stream>>>(src, hi, lo, (int)(n/8));
  };

  cvt(x,    xshi, xslo, (size_t)BT*64);
  cvt(in_W, iwhi, iwlo, (size_t)DM*64);
  cvt(ffe_W1, wfhi,  wflo,  (size_t)DFFN*DM);    // layer-invariant: hoisted
  cvt(ffe_W2, wf2hi, wf2lo, (size_t)DM*DFFN);
  zero_kernel<<<(DM+255)/256, 256, 0, stream>>>(zbuf, DM);

  // input projection + PE -> split
  gemm_split<0,0><<<dim3(BT/128, DM/128), 256, 0, stream>>>(
      xshi, xslo, iwhi, iwlo, in_b, h, (short*)nullptr, (short*)nullptr, BT, DM, 64);
  add_pe_split<<<BT, 256, 0, stream>>>(h, hshi, hslo);

  // ---- encoder ----
  for (int l=0; l<NL; ++l) {
    const size_t wo = (size_t)l*DM*DM, bo_ = (size_t)l*DM;
    cvt(enc_Wq+wo, w0hi, w0lo, MM);
    cvt(enc_Wk+wo, w1hi, w1lo, MM);
    cvt(enc_Wv+wo, w2hi, w2lo, MM);
    cvt(enc_Wo+wo, w3hi, w3lo, MM);
    gemm_split<0,0><<<dim3(32,8),256,0,stream>>>(hshi, hslo, w0hi, w0lo, enc_bq+bo_,
        t0, (short*)nullptr, (short*)nullptr, BT, DM, DM);
    gemm_split<0,0><<<dim3(32,8),256,0,stream>>>(hshi, hslo, w1hi, w1lo, enc_bk+bo_,
        t1, (short*)nullptr, (short*)nullptr, BT, DM, DM);
    gemm_split<0,0><<<dim3(32,8),256,0,stream>>>(hshi, hslo, w2hi, w2lo, enc_bv+bo_,
        t2, (short*)nullptr, (short*)nullptr, BT, DM, DM);
    attn_enc<<<dim3(TT/256, BB*NH),256,0,stream>>>(t0, t1, t2, t3hi, t3lo);
    gemm_split<0,2><<<dim3(32,8),256,0,stream>>>(t3hi, t3lo, w3hi, w3lo, enc_bo+bo_,
        hn, hnhi, hnlo, BT, DM, DM);
    gemm_split<1,1><<<dim3(32,32),256,0,stream>>>(hnhi, hnlo, wfhi, wflo, ffe_b1,
        (float*)nullptr, fmhi, fmlo, BT, DFFN, DM);
    gemm_split<0,0><<<dim3(32,8),256,0,stream>>>(fmhi, fmlo, wf2hi, wf2lo, ffe_b2,
        t4, (short*)nullptr, (short*)nullptr, BT, DM, DFFN);
    ln_add_split<<<BT,256,0,stream>>>(hn, t4, ne_g, ne_b, hshi, hslo);
  }

  // ---- cross-attention K/V cache (bf16; last use of hshi/hslo as activations) ----
  for (int l=0; l<NL; ++l) {
    const size_t wo = (size_t)l*DM*DM, bo_ = (size_t)l*DM;
    cvt(dec_Wk+wo, w0hi, w0lo, MM);
    cvt(dec_Wv+wo, w1hi, w1lo, MM);
    gemm_split<0,3><<<dim3(32,8),256,0,stream>>>(hshi, hslo, w0hi, w0lo, dec_bk+bo_,
        (float*)nullptr, kcb+(size_t)l*BT*DM, (short*)nullptr, BT, DM, DM);
    gemm_split<0,3><<<dim3(32,8),256,0,stream>>>(hshi, hslo, w1hi, w1lo, dec_bv+bo_,
        (float*)nullptr, vcb+(size_t)l*BT*DM, (short*)nullptr, BT, DM, DM);
  }

  // ---- decoder weight setup (once; into dead encoder buffers) ----
  for (int l=0; l<NL; ++l) {
    const size_t wo = (size_t)l*DM*DM;
    cvt(dec_Wq+wo, dwq + (size_t)l*2*MM, dwq + (size_t)l*2*MM + MM, MM);
    cvt(dec_Wk+wo, dwk + (size_t)l*2*MM, dwk + (size_t)l*2*MM + MM, MM);
    cvt(dec_Wv+wo, dwv + (size_t)l*2*MM, dwv + (size_t)l*2*MM + MM, MM);
    cvt(dec_Wo+wo, dwo + (size_t)l*2*MM, dwo + (size_t)l*2*MM + MM, MM);
  }
  cvt(ffd_W1, fw1h, fw1l, (size_t)DFFN*DM);
  cvt(ffd_W2, fw2h, fw2l, (size_t)DM*DFFN);
  // combined cross-Q: Wc = Wq@Wo (row-major split into wch/wcl), bc = Wq@bo + bq
  for (int l=0; l<NL; ++l) {
    const size_t wo = (size_t)l*DM*DM, bo_ = (size_t)l*DM;
    k_transpose<<<1024, 256, 0, stream>>>(dec_Wo+wo, wotf);
    cvt(wotf,      w0hi, w0lo, MM);
    cvt(dec_Wq+wo, w1hi, w1lo, MM);
    gemm_split<0,0><<<dim3(8,8),256,0,stream>>>(w1hi, w1lo, w0hi, w0lo, zbuf,
        wcf, (short*)nullptr, (short*)nullptr, DM, DM, DM);
    k_bc<<<DM, 256, 0, stream>>>(dec_Wq+wo, dec_bo+bo_, dec_bq+bo_, bqo+bo_);
    cvt(wcf, wch + (size_t)l*MM, wcl + (size_t)l*MM, MM);
  }

  #define GD(MRv, grid, ...) do { switch(MRv){ \
    case 1: gemm_dec<1><<<grid,256,0,stream>>>(__VA_ARGS__); break; \
    case 2: gemm_dec<2><<<grid,256,0,stream>>>(__VA_ARGS__); break; \
    case 3: gemm_dec<3><<<grid,256,0,stream>>>(__VA_ARGS__); break; \
    case 4: gemm_dec<4><<<grid,256,0,stream>>>(__VA_ARGS__); break; \
    case 5: gemm_dec<5><<<grid,256,0,stream>>>(__VA_ARGS__); break; \
    default: gemm_dec<6><<<grid,256,0,stream>>>(__VA_ARGS__); break; } } while(0)

  // ---- decoder: 12 kernels/layer ----
  k_init0<<<BB, 256, 0, stream>>>(dphi, dplo);
  for (int s=0; s<NSTEP; ++s){
    const int n = s+1, rows = 4*n;
    const int Mt = (rows + 15) & ~15;
    const int MR = Mt >> 4;
    for (int l=0; l<NL; ++l){
      const short* qh = dwq + (size_t)l*2*MM; const short* ql = qh + MM;
      const short* kh = dwk + (size_t)l*2*MM; const short* kl = kh + MM;
      const short* vh = dwv + (size_t)l*2*MM; const short* vl = vh + MM;
      const short* oh = dwo + (size_t)l*2*MM; const short* ol = oh + MM;
      const short* ch = wch + (size_t)l*MM;   const short* cl = wcl + (size_t)l*MM;
      const float* lbq = dec_bq + (size_t)l*DM;
      const float* lbk = dec_bk + (size_t)l*DM;
      const float* lbv = dec_bv + (size_t)l*DM;
      const float* lbo = dec_bo + (size_t)l*DM;
      const float* lbc = bqo + (size_t)l*DM;
      const short* in_hi = (l==0) ? dphi : dlhi;
      const short* in_lo = (l==0) ? dplo : dllo;
      // self-attn QKV (partials) + attention with inline reduce
      GD(MR, dim3(8,8,3), in_hi,in_lo, qh,ql, kh,kl, vh,vl, part, DM, DM, 8);
      attn_qkv<<<BB*NH,256,0,stream>>>(part, lbq, lbk, lbv, dahi, dalo, n);
      // fused self-O + cross-Q (Wc) -> dq f32
      GD(MR, dim3(8,8,1), dahi,dalo, ch,cl, ch,cl, ch,cl, part, DM, DM, 8);
      reduce_dec<0,0><<<dim3(Mt*4,1),256,0,stream>>>(part, lbc, lbc, lbc,
          dq, dq, dq, (short*)nullptr, (short*)nullptr, DM, 8);
      // cross-attention (bf16 KV cache)
      attn_cross_part<<<dim3(CSPLIT, BB*NH),256,0,stream>>>(dq,
          kcb + (size_t)l*BT*DM, vcb + (size_t)l*BT*DM, opart, mlp, n);
      attn_cross_comb<<<dim3(BB*NH, 6),256,0,stream>>>(opart, mlp, dahi, dalo, n);
      // cross-O -> dbuf f32 + split
      GD(MR, dim3(8,8,1), dahi,dalo, oh,ol, oh,ol, oh,ol, part, DM, DM, 8);
      reduce_dec<0,2><<<dim3(Mt*4,1),256,0,stream>>>(part, lbo, lbo, lbo,
          dbuf, dbuf, dbuf, dxhi, dxlo, DM, 8);
      // FFN
      GD(MR, dim3(32,8,1), dxhi,dxlo, fw1h,fw1l, fw1h,fw1l, fw1h,fw1l, part, DFFN, DM, 8);
      reduce_dec<1,1><<<dim3(Mt*16,1),256,0,stream>>>(part, ffd_b1, ffd_b1, ffd_b1,
          (float*)nullptr,(float*)nullptr,(float*)nullptr, dmhi, dmlo, DFFN, 8);
      GD(MR, dim3(8,16,1), dmhi,dmlo, fw2h,fw2l, fw2h,fw2l, fw2h,fw2l, part, DM, DFFN, 16);
      k_lnr<<<rows,256,0,stream>>>(part, ffd_b2, dbuf, nd_g, nd_b, dbuf, dlhi, dllo);
    }
    k_out<<<BB, 256, 0, stream>>>(dbuf, out_W, out_b, temb_W, temb_b, dout,
        dphi, dplo, s);
  }
  #undef GD
}

// Round 13
// 13215.813 us; speedup vs baseline: 1.6830x; 1.0293x over previous
//
#include <hip/hip_runtime.h>
#include <math.h>

#define DM    1024
#define NH    16
#define DKH   64
#define NL    4
#define DFFN  4096
#define BB    4
#define TT    1024
#define NSTEP 24
#define BT    (BB*TT)      // 4096 encoder rows
#define MD    (BB*NSTEP)   // 96 decoder rows max (packed: row = i*4 + b)
#define CSPLIT 8
#define CKEYS  (TT/CSPLIT) // 128 keys per cross-attn split
#define PSTRIDE ((size_t)MD*DM)        // partial plane stride (f32), N=DM
#define PSTRIDE_F ((size_t)MD*DFFN)    // partial plane stride (f32), N=DFFN

typedef __attribute__((ext_vector_type(8))) short s16x8;
typedef __attribute__((ext_vector_type(4))) short s16x4;
typedef __attribute__((ext_vector_type(4))) float f32x4;

__device__ inline short f2b(float f){
  unsigned u = __float_as_uint(f);
  u += 0x7fffu + ((u>>16)&1u);          // round-to-nearest-even
  return (short)(u>>16);
}
__device__ inline float b2f(short h){
  return __uint_as_float(((unsigned)(unsigned short)h)<<16);
}

__device__ inline float wave_sum(float v){
  #pragma unroll
  for (int off=1; off<64; off<<=1) v += __shfl_xor(v, off, 64);
  return v;
}

// ---------------- f32 -> (hi,lo) bf16 split ----------------
__global__ __launch_bounds__(256)
void split_kernel(const float* __restrict__ X, short* __restrict__ Hi,
                  short* __restrict__ Lo, int n8)
{
  const size_t i = (size_t)blockIdx.x*256 + threadIdx.x;
  if (i >= (size_t)n8) return;
  const float4 v0 = *(const float4*)(X + i*8);
  const float4 v1 = *(const float4*)(X + i*8 + 4);
  const float f[8] = {v0.x,v0.y,v0.z,v0.w,v1.x,v1.y,v1.z,v1.w};
  s16x8 hv, lv;
  #pragma unroll
  for (int e=0;e<8;e++){
    const short h = f2b(f[e]);
    hv[e] = h;
    lv[e] = f2b(f[e] - b2f(h));
  }
  *(s16x8*)(Hi + i*8) = hv;
  *(s16x8*)(Lo + i*8) = lv;
}

__global__ void zero_kernel(float* __restrict__ p, int n) {
  int i = blockIdx.x*256 + threadIdx.x;
  if (i < n) p[i] = 0.f;
}

// f32 1024x1024 transpose
__global__ __launch_bounds__(256)
void k_transpose(const float* __restrict__ A, float* __restrict__ At)
{
  __shared__ float tile[32][33];
  const int bx = blockIdx.x & 31, by = blockIdx.x >> 5;
  const int x0 = bx*32, y0 = by*32;
  const int tid = threadIdx.x;
  for (int i=tid; i<1024; i+=256){
    const int r = i>>5, c = i&31;
    tile[r][c] = A[(size_t)(y0+r)*DM + x0+c];
  }
  __syncthreads();
  for (int i=tid; i<1024; i+=256){
    const int r = i>>5, c = i&31;
    At[(size_t)(x0+r)*DM + y0+c] = tile[c][r];
  }
}

// bc[row] = dot(Wq[row,:], bo) + bq[row]
__global__ __launch_bounds__(256)
void k_bc(const float* __restrict__ Wq, const float* __restrict__ bo,
          const float* __restrict__ bq, float* __restrict__ bc)
{
  const int row = blockIdx.x, tid = threadIdx.x;
  float s = 0.f;
  for (int j=tid; j<DM; j+=256) s += Wq[(size_t)row*DM + j]*bo[j];
  s = wave_sum(s);
  __shared__ float r4[4];
  if ((tid&63)==0) r4[tid>>6] = s;
  __syncthreads();
  if (tid==0) bc[row] = r4[0]+r4[1]+r4[2]+r4[3] + bq[row];
}

// h[row] + pe[row%TT] -> split bf16 (encoder)
__global__ __launch_bounds__(256)
void add_pe_split(const float* __restrict__ h, short* __restrict__ Hi,
                  short* __restrict__ Lo)
{
  const int row = blockIdx.x;
  const int pos = row & (TT-1);
  const int d = threadIdx.x*4;
  const float4 a = *(const float4*)(h + (size_t)row*DM + d);
  const float c1 = -9.210340371976184f / 1024.0f;
  const float e0 = expf((float)d * c1);
  const float e1 = expf((float)(d+2) * c1);
  const float a0 = (float)pos * e0, a1 = (float)pos * e1;
  const float v[4] = {a.x + sinf(a0), a.y + cosf(a0), a.z + sinf(a1), a.w + cosf(a1)};
  s16x4 hv, lv;
  #pragma unroll
  for (int e=0;e<4;e++){
    const short hb = f2b(v[e]);
    hv[e] = hb;
    lv[e] = f2b(v[e] - b2f(hb));
  }
  *(s16x4*)(Hi + (size_t)row*DM + d) = hv;
  *(s16x4*)(Lo + (size_t)row*DM + d) = lv;
}

// ---------------- split-bf16 MFMA GEMM (encoder/setup): C = A @ W^T + bias ------
// OUT_MODE: 0 f32; 1 split; 2 both; 3 plain-bf16 Chi.
template<int ACT, int OUT_MODE>
__global__ __launch_bounds__(256, 2)
void gemm_split(const short* __restrict__ Ahi, const short* __restrict__ Alo,
                const short* __restrict__ Bhi, const short* __restrict__ Blo,
                const float* __restrict__ bias,
                float* __restrict__ C, short* __restrict__ Chi, short* __restrict__ Clo,
                int M, int N, int K)
{
  __shared__ __align__(16) short lA[2][128][40];
  __shared__ __align__(16) short lB[2][128][40];
  const int tid = threadIdx.x;
  const int m0 = blockIdx.x*128, n0 = blockIdx.y*128;
  const int lane = tid & 63, w = tid >> 6;
  const int wr = w >> 1, wc = w & 1;
  const int fr = lane & 15, fq = lane >> 4;

  f32x4 acc[4][4];
  #pragma unroll
  for (int i=0;i<4;i++)
    #pragma unroll
    for (int j=0;j<4;j++) acc[i][j] = (f32x4){0.f,0.f,0.f,0.f};

  for (int k0 = 0; k0 < K; k0 += 32) {
    __syncthreads();
    #pragma unroll
    for (int j=0;j<2;j++){
      const int cc = tid + j*256;
      const int row = cc >> 2, kq = cc & 3;
      const size_t ga = (size_t)(m0+row)*K + k0 + kq*8;
      const size_t gb = (size_t)(n0+row)*K + k0 + kq*8;
      *(s16x8*)&lA[0][row][kq*8] = *(const s16x8*)(Ahi + ga);
      *(s16x8*)&lA[1][row][kq*8] = *(const s16x8*)(Alo + ga);
      *(s16x8*)&lB[0][row][kq*8] = *(const s16x8*)(Bhi + gb);
      *(s16x8*)&lB[1][row][kq*8] = *(const s16x8*)(Blo + gb);
    }
    __syncthreads();
    s16x8 ah[4], al[4], bh[4], bl[4];
    #pragma unroll
    for (int i=0;i<4;i++){
      ah[i] = *(const s16x8*)&lA[0][wr*64+i*16+fr][fq*8];
      al[i] = *(const s16x8*)&lA[1][wr*64+i*16+fr][fq*8];
    }
    #pragma unroll
    for (int j=0;j<4;j++){
      bh[j] = *(const s16x8*)&lB[0][wc*64+j*16+fr][fq*8];
      bl[j] = *(const s16x8*)&lB[1][wc*64+j*16+fr][fq*8];
    }
    #pragma unroll
    for (int i=0;i<4;i++)
      #pragma unroll
      for (int j=0;j<4;j++){
        acc[i][j] = __builtin_amdgcn_mfma_f32_16x16x32_bf16(ah[i], bh[j], acc[i][j], 0,0,0);
        acc[i][j] = __builtin_amdgcn_mfma_f32_16x16x32_bf16(ah[i], bl[j], acc[i][j], 0,0,0);
        acc[i][j] = __builtin_amdgcn_mfma_f32_16x16x32_bf16(al[i], bh[j], acc[i][j], 0,0,0);
      }
  }
  #pragma unroll
  for (int j=0;j<4;j++){
    const int col = n0 + wc*64 + j*16 + fr;
    const float bv = bias[col];
    #pragma unroll
    for (int i=0;i<4;i++){
      const int row0 = m0 + wr*64 + i*16 + fq*4;
      #pragma unroll
      for (int r=0;r<4;r++){
        float v = acc[i][j][r] + bv;
        if (ACT==1) v = fmaxf(v, 0.f);
        const size_t idx = (size_t)(row0+r)*N + col;
        if (OUT_MODE==0 || OUT_MODE==2) C[idx] = v;
        if (OUT_MODE==1 || OUT_MODE==2){
          const short hb = f2b(v);
          Chi[idx] = hb;
          Clo[idx] = f2b(v - b2f(hb));
        }
        if (OUT_MODE==3) Chi[idx] = f2b(v);
      }
    }
  }
}

// ---------------- encoder self-attention (flash, thread-per-q-row, split out) ----
__global__ __launch_bounds__(256)
void attn_enc(const float* __restrict__ Qg, const float* __restrict__ Kg,
              const float* __restrict__ Vg, short* __restrict__ Ohi,
              short* __restrict__ Olo)
{
  const int bh = blockIdx.y;
  const int b = bh >> 4, hh = bh & 15;
  const int row = blockIdx.x*256 + threadIdx.x;
  const size_t base = ((size_t)b*TT)*DM + hh*DKH;
  float q[64];
  {
    const float* qp = Qg + base + (size_t)row*DM;
    #pragma unroll
    for (int d4=0; d4<16; d4++){
      const float4 v = *(const float4*)(qp + d4*4);
      q[d4*4+0]=v.x; q[d4*4+1]=v.y; q[d4*4+2]=v.z; q[d4*4+3]=v.w;
    }
  }
  float o[64];
  #pragma unroll
  for (int d=0;d<64;d++) o[d]=0.f;
  float m = -INFINITY, l = 0.f;
  __shared__ float Ks[64][68];
  __shared__ float Vs[64][68];
  for (int kt=0; kt<TT; kt+=64) {
    __syncthreads();
    #pragma unroll
    for (int t=0;t<4;t++){
      const int fi = threadIdx.x + t*256;
      const int j = fi>>4, dq = fi&15;
      *(float4*)&Ks[j][dq*4] = *(const float4*)(Kg + base + (size_t)(kt+j)*DM + dq*4);
      *(float4*)&Vs[j][dq*4] = *(const float4*)(Vg + base + (size_t)(kt+j)*DM + dq*4);
    }
    __syncthreads();
    for (int j=0;j<64;j++){
      float s0=0.f,s1=0.f,s2=0.f,s3=0.f;
      #pragma unroll
      for (int d=0; d<64; d+=4){
        s0 = fmaf(q[d+0], Ks[j][d+0], s0);
        s1 = fmaf(q[d+1], Ks[j][d+1], s1);
        s2 = fmaf(q[d+2], Ks[j][d+2], s2);
        s3 = fmaf(q[d+3], Ks[j][d+3], s3);
      }
      const float s = ((s0+s1)+(s2+s3)) * 0.125f;
      if (s > m) {
        const float f = __expf(m - s);
        l *= f;
        #pragma unroll
        for (int d=0;d<64;d++) o[d] *= f;
        m = s;
      }
      const float p = __expf(s - m);
      l += p;
      #pragma unroll
      for (int d=0;d<64;d++) o[d] = fmaf(p, Vs[j][d], o[d]);
    }
  }
  const float inv = 1.f / l;
  #pragma unroll
  for (int d8=0; d8<8; d8++){
    s16x8 hv, lv;
    #pragma unroll
    for (int e=0;e<8;e++){
      const float f = o[d8*8+e]*inv;
      const short hb = f2b(f);
      hv[e] = hb;
      lv[e] = f2b(f - b2f(hb));
    }
    *(s16x8*)(Ohi + base + (size_t)row*DM + d8*8) = hv;
    *(s16x8*)(Olo + base + (size_t)row*DM + d8*8) = lv;
  }
}

// encoder LayerNorm: split bf16 out
__global__ __launch_bounds__(256)
void ln_add_split(const float* __restrict__ X, const float* __restrict__ Y,
                  const float* __restrict__ g, const float* __restrict__ be,
                  short* __restrict__ Ohi, short* __restrict__ Olo)
{
  const size_t row = blockIdx.x;
  const int tid = threadIdx.x;
  const float4 a = *(const float4*)(X + row*DM + tid*4);
  const float4 b = *(const float4*)(Y + row*DM + tid*4);
  const float v0=a.x+b.x, v1=a.y+b.y, v2=a.z+b.z, v3=a.w+b.w;
  float s = v0+v1+v2+v3;
  float q = v0*v0+v1*v1+v2*v2+v3*v3;
  s = wave_sum(s); q = wave_sum(q);
  __shared__ float rs[4], rq[4];
  if ((tid&63)==0){ rs[tid>>6]=s; rq[tid>>6]=q; }
  __syncthreads();
  const float S = rs[0]+rs[1]+rs[2]+rs[3];
  const float Q = rq[0]+rq[1]+rq[2]+rq[3];
  const float mean = S * (1.f/DM);
  const float var  = Q * (1.f/DM) - mean*mean;
  const float rstd = rsqrtf(var + 1e-5f);
  const float4 gv = *(const float4*)(g  + tid*4);
  const float4 bv = *(const float4*)(be + tid*4);
  const float v[4] = {(v0-mean)*rstd*gv.x + bv.x, (v1-mean)*rstd*gv.y + bv.y,
                      (v2-mean)*rstd*gv.z + bv.z, (v3-mean)*rstd*gv.w + bv.w};
  s16x4 hv, lv;
  #pragma unroll
  for (int e=0;e<4;e++){
    const short hb = f2b(v[e]);
    hv[e] = hb;
    lv[e] = f2b(v[e] - b2f(hb));
  }
  *(s16x4*)(Ohi + row*DM + tid*4) = hv;
  *(s16x4*)(Olo + row*DM + tid*4) = lv;
}

// ================= decoder (LDS-staged split-MFMA, K-split partials) ==

// A[Mt x K] split bf16 (packed rows), W[N x K]^T split bf16 (3 selectable),
// partials P[z][ks][MD][N] f32. Tile: Mt x 128, 4 waves (32 cols each).
template<int MR>
__global__ __launch_bounds__(256)
void gemm_dec(const short* __restrict__ Ahi, const short* __restrict__ Alo,
              const short* __restrict__ B0hi, const short* __restrict__ B0lo,
              const short* __restrict__ B1hi, const short* __restrict__ B1lo,
              const short* __restrict__ B2hi, const short* __restrict__ B2lo,
              float* __restrict__ part, int N, int K, int KS)
{
  const short* Bhi = (blockIdx.z==0) ? B0hi : (blockIdx.z==1 ? B1hi : B2hi);
  const short* Blo = (blockIdx.z==0) ? B0lo : (blockIdx.z==1 ? B1lo : B2lo);
  float* P = part + ((size_t)blockIdx.z*KS + blockIdx.y)*(size_t)MD*N;
  const int KK = K / KS;
  const int kbase = blockIdx.y * KK;
  const int n0 = blockIdx.x * 128;
  __shared__ __align__(16) short lA[2][96][40];
  __shared__ __align__(16) short lB[2][128][40];
  const int tid = threadIdx.x;
  const int lane = tid & 63, w = tid >> 6;
  const int fr = lane & 15, fq = lane >> 4;
  constexpr int CH = MR*128;                 // A staging chunks (Mt rows x 8)

  f32x4 acc[MR][2];
  #pragma unroll
  for (int i=0;i<MR;i++){ acc[i][0]=(f32x4){0,0,0,0}; acc[i][1]=(f32x4){0,0,0,0}; }

  for (int k0 = kbase; k0 < kbase + KK; k0 += 32) {
    __syncthreads();
    #pragma unroll
    for (int t=0; t<(CH+255)/256; t++){
      const int cc = tid + t*256;
      if (cc < CH){
        const int row = cc>>3, hl = (cc>>2)&1, kq = cc&3;
        const short* src = hl ? Alo : Ahi;
        *(s16x8*)&lA[hl][row][kq*8] = *(const s16x8*)(src + (size_t)row*K + k0 + kq*8);
      }
    }
    #pragma unroll
    for (int t=0; t<4; t++){
      const int cc = tid + t*256;
      const int row = cc>>3, hl = (cc>>2)&1, kq = cc&3;
      const short* src = hl ? Blo : Bhi;
      *(s16x8*)&lB[hl][row][kq*8] = *(const s16x8*)(src + (size_t)(n0+row)*K + k0 + kq*8);
    }
    __syncthreads();
    s16x8 bh[2], bl[2];
    #pragma unroll
    for (int j=0;j<2;j++){
      bh[j] = *(const s16x8*)&lB[0][w*32+j*16+fr][fq*8];
      bl[j] = *(const s16x8*)&lB[1][w*32+j*16+fr][fq*8];
    }
    #pragma unroll
    for (int i=0;i<MR;i++){
      const s16x8 ah = *(const s16x8*)&lA[0][i*16+fr][fq*8];
      const s16x8 al = *(const s16x8*)&lA[1][i*16+fr][fq*8];
      #pragma unroll
      for (int j=0;j<2;j++){
        acc[i][j] = __builtin_amdgcn_mfma_f32_16x16x32_bf16(ah, bh[j], acc[i][j], 0,0,0);
        acc[i][j] = __builtin_amdgcn_mfma_f32_16x16x32_bf16(ah, bl[j], acc[i][j], 0,0,0);
        acc[i][j] = __builtin_amdgcn_mfma_f32_16x16x32_bf16(al, bh[j], acc[i][j], 0,0,0);
      }
    }
  }
  #pragma unroll
  for (int j=0;j<2;j++){
    const int col = n0 + w*32 + j*16 + fr;
    #pragma unroll
    for (int i=0;i<MR;i++){
      const int row0 = i*16 + fq*4;
      #pragma unroll
      for (int r=0;r<4;r++)
        P[(size_t)(row0+r)*N + col] = acc[i][j][r];
    }
  }
}

// gemm_dec variant: A comes from 8 f32 partial planes (reduced+bias(+relu)+split
// inline during staging). Same fragment math, same output partials.
template<int MR, int AACT>
__global__ __launch_bounds__(256)
void gemm_dec_r(const float* __restrict__ PA, const float* __restrict__ biasA,
                const short* __restrict__ Bhi, const short* __restrict__ Blo,
                float* __restrict__ part, int N, int K, int KS)
{
  // PA planes stride = MD*K
  float* P = part + (size_t)blockIdx.y*(size_t)MD*N;
  const int KK = K / KS;
  const int kbase = blockIdx.y * KK;
  const int n0 = blockIdx.x * 128;
  __shared__ __align__(16) short lA[2][96][40];
  __shared__ __align__(16) short lB[2][128][40];
  const int tid = threadIdx.x;
  const int lane = tid & 63, w = tid >> 6;
  const int fr = lane & 15, fq = lane >> 4;
  constexpr int CH = MR*128;                 // A quads: MR*16 rows x 8 quads
  const size_t psA = (size_t)MD*K;

  f32x4 acc[MR][2];
  #pragma unroll
  for (int i=0;i<MR;i++){ acc[i][0]=(f32x4){0,0,0,0}; acc[i][1]=(f32x4){0,0,0,0}; }

  for (int k0 = kbase; k0 < kbase + KK; k0 += 32) {
    __syncthreads();
    #pragma unroll
    for (int t=0; t<(CH+255)/256; t++){
      const int cc = tid + t*256;
      if (cc < CH){
        const int row = cc>>3, q = cc&7;
        const int k = k0 + q*4;
        float4 a = *(const float4*)(biasA + k);
        const float* src = PA + (size_t)row*K + k;
        #pragma unroll
        for (int p=0;p<8;p++){
          const float4 v = *(const float4*)(src + (size_t)p*psA);
          a.x+=v.x; a.y+=v.y; a.z+=v.z; a.w+=v.w;
        }
        if (AACT){
          a.x=fmaxf(a.x,0.f); a.y=fmaxf(a.y,0.f);
          a.z=fmaxf(a.z,0.f); a.w=fmaxf(a.w,0.f);
        }
        const float vv[4] = {a.x,a.y,a.z,a.w};
        s16x4 hv, lv;
        #pragma unroll
        for (int e=0;e<4;e++){
          const short hb = f2b(vv[e]);
          hv[e] = hb;
          lv[e] = f2b(vv[e] - b2f(hb));
        }
        *(s16x4*)&lA[0][row][q*4] = hv;
        *(s16x4*)&lA[1][row][q*4] = lv;
      }
    }
    #pragma unroll
    for (int t=0; t<4; t++){
      const int cc = tid + t*256;
      const int row = cc>>3, hl = (cc>>2)&1, kq = cc&3;
      const short* src = hl ? Blo : Bhi;
      *(s16x8*)&lB[hl][row][kq*8] = *(const s16x8*)(src + (size_t)(n0+row)*K + k0 + kq*8);
    }
    __syncthreads();
    s16x8 bh[2], bl[2];
    #pragma unroll
    for (int j=0;j<2;j++){
      bh[j] = *(const s16x8*)&lB[0][w*32+j*16+fr][fq*8];
      bl[j] = *(const s16x8*)&lB[1][w*32+j*16+fr][fq*8];
    }
    #pragma unroll
    for (int i=0;i<MR;i++){
      const s16x8 ah = *(const s16x8*)&lA[0][i*16+fr][fq*8];
      const s16x8 al = *(const s16x8*)&lA[1][i*16+fr][fq*8];
      #pragma unroll
      for (int j=0;j<2;j++){
        acc[i][j] = __builtin_amdgcn_mfma_f32_16x16x32_bf16(ah, bh[j], acc[i][j], 0,0,0);
        acc[i][j] = __builtin_amdgcn_mfma_f32_16x16x32_bf16(ah, bl[j], acc[i][j], 0,0,0);
        acc[i][j] = __builtin_amdgcn_mfma_f32_16x16x32_bf16(al, bh[j], acc[i][j], 0,0,0);
      }
    }
  }
  #pragma unroll
  for (int j=0;j<2;j++){
    const int col = n0 + w*32 + j*16 + fr;
    #pragma unroll
    for (int i=0;i<MR;i++){
      const int row0 = i*16 + fq*4;
      #pragma unroll
      for (int r=0;r<4;r++)
        P[(size_t)(row0+r)*N + col] = acc[i][j][r];
    }
  }
}

// self-attention with inline QKV partial-reduce (KS=8, layout [3][8][MD][DM]).
// 64 blocks = (b,hh). Split out.
__global__ __launch_bounds__(256)
void attn_qkv(const float* __restrict__ part,
              const float* __restrict__ lbq, const float* __restrict__ lbk,
              const float* __restrict__ lbv,
              short* __restrict__ Ohi, short* __restrict__ Olo, int n)
{
  const int bh = blockIdx.x, b = bh >> 4, hh = bh & 15;
  const size_t obase = (size_t)b*DM + hh*DKH;
  __shared__ float Qs[NSTEP][68], Ks[NSTEP][68], Vs[NSTEP][68];
  __shared__ float P[NSTEP][28];
  const int tid = threadIdx.x;
  for (int t = tid; t < 3*n*16; t += 256){
    const int tensor = t / (n*16);
    const int fi = t - tensor*(n*16);
    const int row = fi >> 4, q4 = fi & 15;
    const int col0 = hh*DKH + q4*4;
    const float* bias = (tensor==0?lbq:(tensor==1?lbk:lbv));
    float4 a;
    a.x = bias[col0]; a.y = bias[col0+1]; a.z = bias[col0+2]; a.w = bias[col0+3];
    const size_t eoff = (size_t)(row*4+b)*DM + col0;
    #pragma unroll
    for (int ks=0; ks<8; ks++){
      const float4 p = *(const float4*)(part + (size_t)(tensor*8+ks)*PSTRIDE + eoff);
      a.x+=p.x; a.y+=p.y; a.z+=p.z; a.w+=p.w;
    }
    float (*dst)[68] = (tensor==0?Qs:(tensor==1?Ks:Vs));
    *(float4*)&dst[row][q4*4] = a;
  }
  __syncthreads();
  for (int idx = tid; idx < n*n; idx += 256){
    const int i = idx / n, j = idx - i*n;
    float s0=0.f,s1=0.f,s2=0.f,s3=0.f;
    #pragma unroll
    for (int d=0; d<64; d+=4){
      s0 = fmaf(Qs[i][d+0], Ks[j][d+0], s0);
      s1 = fmaf(Qs[i][d+1], Ks[j][d+1], s1);
      s2 = fmaf(Qs[i][d+2], Ks[j][d+2], s2);
      s3 = fmaf(Qs[i][d+3], Ks[j][d+3], s3);
    }
    P[i][j] = ((s0+s1)+(s2+s3))*0.125f;
  }
  __syncthreads();
  if (tid < n){
    float mm = -INFINITY;
    for (int j=0;j<n;j++) mm = fmaxf(mm, P[tid][j]);
    float l = 0.f;
    for (int j=0;j<n;j++){ const float p = __expf(P[tid][j]-mm); P[tid][j]=p; l+=p; }
    const float inv = 1.f/l;
    for (int j=0;j<n;j++) P[tid][j] *= inv;
  }
  __syncthreads();
  for (int idx = tid; idx < n*64; idx += 256){
    const int i = idx >> 6, d = idx & 63;
    float s = 0.f;
    for (int j=0;j<n;j++) s = fmaf(P[i][j], Vs[j][d], s);
    const short hb = f2b(s);
    const size_t o = obase + (size_t)(i*4)*DM + d;
    Ohi[o] = hb;
    Olo[o] = f2b(s - b2f(hb));
  }
}

// cross-attn partials; Q reduced inline from 8 partial planes + bc bias.
// grid (CSPLIT, 64)
__global__ __launch_bounds__(256)
void attn_cross_part(const float* __restrict__ Qpart, const float* __restrict__ lbc,
                     const short* __restrict__ Kc, const short* __restrict__ Vc,
                     float* __restrict__ opart, float* __restrict__ mlpart, int n)
{
  const int ks = blockIdx.x, bh = blockIdx.y;
  const int b = bh >> 4, hh = bh & 15;
  __shared__ float Qs[NSTEP][68];
  __shared__ short KVs[CKEYS][72];
  __shared__ float S[NSTEP][132];
  const int tid = threadIdx.x;
  for (int t=tid; t<n*16; t+=256){
    const int row = t>>4, q4 = t&15;
    const int col0 = hh*DKH + q4*4;
    float4 a;
    a.x = lbc[col0]; a.y = lbc[col0+1]; a.z = lbc[col0+2]; a.w = lbc[col0+3];
    const size_t eoff = (size_t)(row*4+b)*DM + col0;
    #pragma unroll
    for (int p=0; p<8; p++){
      const float4 v = *(const float4*)(Qpart + (size_t)p*PSTRIDE + eoff);
      a.x+=v.x; a.y+=v.y; a.z+=v.z; a.w+=v.w;
    }
    *(float4*)&Qs[row][q4*4] = a;
  }
  const size_t kbase = ((size_t)b*TT + (size_t)ks*CKEYS)*DM + hh*DKH;
  for (int t=tid; t<CKEYS*8; t+=256){
    const int row = t>>3, d8 = t&7;
    *(s16x8*)&KVs[row][d8*8] = *(const s16x8*)(Kc + kbase + (size_t)row*DM + d8*8);
  }
  __syncthreads();
  for (int idx=tid; idx<n*128; idx+=256){
    const int i = idx >> 7, j = idx & 127;
    float s0=0.f,s1=0.f,s2=0.f,s3=0.f;
    #pragma unroll
    for (int d=0; d<64; d+=4){
      s0 = fmaf(Qs[i][d+0], b2f(KVs[j][d+0]), s0);
      s1 = fmaf(Qs[i][d+1], b2f(KVs[j][d+1]), s1);
      s2 = fmaf(Qs[i][d+2], b2f(KVs[j][d+2]), s2);
      s3 = fmaf(Qs[i][d+3], b2f(KVs[j][d+3]), s3);
    }
    S[i][j] = ((s0+s1)+(s2+s3))*0.125f;
  }
  __syncthreads();
  for (int t=tid; t<CKEYS*8; t+=256){         // V over K buffer
    const int row = t>>3, d8 = t&7;
    *(s16x8*)&KVs[row][d8*8] = *(const s16x8*)(Vc + kbase + (size_t)row*DM + d8*8);
  }
  if (tid < n){
    float mm=-INFINITY;
    for (int j=0;j<CKEYS;j++) mm = fmaxf(mm, S[tid][j]);
    float l=0.f;
    for (int j=0;j<CKEYS;j++){ const float p=__expf(S[tid][j]-mm); S[tid][j]=p; l+=p; }
    mlpart[((size_t)bh*CSPLIT+ks)*(2*NSTEP) + tid*2+0] = mm;
    mlpart[((size_t)bh*CSPLIT+ks)*(2*NSTEP) + tid*2+1] = l;
  }
  __syncthreads();
  for (int idx=tid; idx<n*64; idx+=256){
    const int i = idx >> 6, d = idx & 63;
    float s=0.f;
    for (int j=0;j<CKEYS;j++) s = fmaf(S[i][j], b2f(KVs[j][d]), s);
    opart[(((size_t)bh*CSPLIT+ks)*NSTEP + i)*DKH + d] = s;
  }
}

__global__ __launch_bounds__(256)
void attn_cross_comb(const float* __restrict__ opart, const float* __restrict__ mlpart,
                     short* __restrict__ Ohi, short* __restrict__ Olo, int n)
{
  const int bh = blockIdx.x;
  const int idx = blockIdx.y*256 + threadIdx.x;
  const int i = idx >> 6, d = idx & 63;
  if (i >= n) return;
  float M = -INFINITY;
  #pragma unroll
  for (int s=0;s<CSPLIT;s++)
    M = fmaxf(M, mlpart[((size_t)bh*CSPLIT+s)*(2*NSTEP) + i*2]);
  float acc = 0.f, L = 0.f;
  #pragma unroll
  for (int s=0;s<CSPLIT;s++){
    const float mm = mlpart[((size_t)bh*CSPLIT+s)*(2*NSTEP) + i*2+0];
    const float ll = mlpart[((size_t)bh*CSPLIT+s)*(2*NSTEP) + i*2+1];
    const float f = __expf(mm - M);
    acc = fmaf(f, opart[(((size_t)bh*CSPLIT+s)*NSTEP + i)*DKH + d], acc);
    L   = fmaf(f, ll, L);
  }
  const int b = bh >> 4, hh = bh & 15;
  const float v = acc / L;
  const short hb = f2b(v);
  const size_t o = ((size_t)(i*4+b))*DM + hh*DKH + d;
  Ohi[o] = hb;
  Olo[o] = f2b(v - b2f(hb));
}

// LN: reduce FFN2 partials(16) + fb2 + residual (reduce crossO partials(8) + lbo)
// -> dbuf f32 + split. rows blocks.
__global__ __launch_bounds__(256)
void k_lnr(const float* __restrict__ partF, const float* __restrict__ fb2,
           const float* __restrict__ partR, const float* __restrict__ lbo,
           const float* __restrict__ g, const float* __restrict__ be,
           float* __restrict__ Outf, short* __restrict__ Ohi, short* __restrict__ Olo)
{
  const int row = blockIdx.x;
  __shared__ float rs[4], rq[4];
  const int tid = threadIdx.x;
  float a0,a1,a2,a3;
  {
    const float4 bv = *(const float4*)(fb2 + tid*4);
    a0=bv.x; a1=bv.y; a2=bv.z; a3=bv.w;
  }
  #pragma unroll
  for (int ks=0; ks<16; ks++){
    const float4 p = *(const float4*)(partF + (size_t)ks*PSTRIDE + (size_t)row*DM + tid*4);
    a0+=p.x; a1+=p.y; a2+=p.z; a3+=p.w;
  }
  float r0,r1,r2,r3;
  {
    const float4 bv = *(const float4*)(lbo + tid*4);
    r0=bv.x; r1=bv.y; r2=bv.z; r3=bv.w;
  }
  #pragma unroll
  for (int ks=0; ks<8; ks++){
    const float4 p = *(const float4*)(partR + (size_t)ks*PSTRIDE + (size_t)row*DM + tid*4);
    r0+=p.x; r1+=p.y; r2+=p.z; r3+=p.w;
  }
  const float v0=a0+r0, v1=a1+r1, v2=a2+r2, v3=a3+r3;
  float s = v0+v1+v2+v3;
  float q = v0*v0+v1*v1+v2*v2+v3*v3;
  s = wave_sum(s); q = wave_sum(q);
  if ((tid&63)==0){ rs[tid>>6]=s; rq[tid>>6]=q; }
  __syncthreads();
  const float S = rs[0]+rs[1]+rs[2]+rs[3];
  const float Q = rq[0]+rq[1]+rq[2]+rq[3];
  const float mean = S * (1.f/DM);
  const float var  = Q * (1.f/DM) - mean*mean;
  const float rstd = rsqrtf(var + 1e-5f);
  const float4 gv = *(const float4*)(g  + tid*4);
  const float4 bv2 = *(const float4*)(be + tid*4);
  const float v[4] = {(v0-mean)*rstd*gv.x + bv2.x, (v1-mean)*rstd*gv.y + bv2.y,
                      (v2-mean)*rstd*gv.z + bv2.z, (v3-mean)*rstd*gv.w + bv2.w};
  float4 of; of.x=v[0]; of.y=v[1]; of.z=v[2]; of.w=v[3];
  *(float4*)(Outf + (size_t)row*DM + tid*4) = of;
  s16x4 hv, lv;
  #pragma unroll
  for (int e=0;e<4;e++){
    const short hb = f2b(v[e]);
    hv[e] = hb;
    lv[e] = f2b(v[e] - b2f(hb));
  }
  *(s16x4*)(Ohi + (size_t)row*DM + tid*4) = hv;
  *(s16x4*)(Olo + (size_t)row*DM + tid*4) = lv;
}

// final projection + write next step's split input (emb + PE). 4 blocks.
__global__ __launch_bounds__(256)
void k_out(const float* __restrict__ Dv, const float* __restrict__ outW,
           const float* __restrict__ outB, const float* __restrict__ tembW,
           const float* __restrict__ tembB, float* __restrict__ dout,
           short* __restrict__ Dphi, short* __restrict__ Dplo, int s)
{
  const int b = blockIdx.x;
  __shared__ float red[4];
  __shared__ float stepv;
  const int tid = threadIdx.x;
  const float* drow = Dv + ((size_t)(s*4 + b))*DM;
  const float4 dv4 = *(const float4*)(drow + tid*4);
  const float4 wv = *(const float4*)(outW + tid*4);
  float p = dv4.x*wv.x + dv4.y*wv.y + dv4.z*wv.z + dv4.w*wv.w;
  p = wave_sum(p);
  if ((tid&63)==0) red[tid>>6] = p;
  __syncthreads();
  if (tid==0){
    const float sv = red[0]+red[1]+red[2]+red[3] + outB[0];
    stepv = sv;
    dout[b*NSTEP + s] = sv;
  }
  __syncthreads();
  const float sv = stepv;
  if (s+1 < NSTEP){
    const int d = tid*4, pos = s+1;
    const float4 tw = *(const float4*)(tembW + d);
    const float4 tb = *(const float4*)(tembB + d);
    const float c1 = -9.210340371976184f / 1024.0f;
    const float e0 = expf((float)d * c1);
    const float e1 = expf((float)(d+2) * c1);
    const float a0 = (float)pos * e0, a1 = (float)pos * e1;
    const float v[4] = { fmaf(sv, tw.x, tb.x) + sinf(a0),
                         fmaf(sv, tw.y, tb.y) + cosf(a0),
                         fmaf(sv, tw.z, tb.z) + sinf(a1),
                         fmaf(sv, tw.w, tb.w) + cosf(a1) };
    s16x4 hv, lv;
    #pragma unroll
    for (int e=0;e<4;e++){
      const short hb = f2b(v[e]);
      hv[e] = hb;
      lv[e] = f2b(v[e] - b2f(hb));
    }
    const size_t o = (size_t)(pos*4 + b)*DM + d;
    *(s16x4*)(Dphi + o) = hv;
    *(s16x4*)(Dplo + o) = lv;
  }
}

// step-0 input rows: split(0 + pe[0])
__global__ __launch_bounds__(256)
void k_init0(short* __restrict__ Dphi, short* __restrict__ Dplo)
{
  const int b = blockIdx.x;
  const int d = threadIdx.x*4;
  const float v[4] = {0.f, 1.f, 0.f, 1.f};   // sin(0), cos(0)
  s16x4 hv, lv;
  #pragma unroll
  for (int e=0;e<4;e++){
    const short hb = f2b(v[e]);
    hv[e] = hb;
    lv[e] = f2b(v[e] - b2f(hb));
  }
  *(s16x4*)(Dphi + (size_t)b*DM + d) = hv;
  *(s16x4*)(Dplo + (size_t)b*DM + d) = lv;
}

// ---------------- orchestration ----------------
extern "C" void kernel_launch(void* const* d_in, const int* in_sizes, int n_in,
                              void* d_out, int out_size, void* d_ws, size_t ws_size,
                              hipStream_t stream)
{
  (void)in_sizes; (void)n_in; (void)out_size; (void)ws_size;
  const float* x      = (const float*)d_in[0];
  const float* in_W   = (const float*)d_in[1];
  const float* in_b   = (const float*)d_in[2];
  const float* enc_Wq = (const float*)d_in[3];
  const float* enc_bq = (const float*)d_in[4];
  const float* enc_Wk = (const float*)d_in[5];
  const float* enc_bk = (const float*)d_in[6];
  const float* enc_Wv = (const float*)d_in[7];
  const float* enc_bv = (const float*)d_in[8];
  const float* enc_Wo = (const float*)d_in[9];
  const float* enc_bo = (const float*)d_in[10];
  const float* dec_Wq = (const float*)d_in[11];
  const float* dec_bq = (const float*)d_in[12];
  const float* dec_Wk = (const float*)d_in[13];
  const float* dec_bk = (const float*)d_in[14];
  const float* dec_Wv = (const float*)d_in[15];
  const float* dec_bv = (const float*)d_in[16];
  const float* dec_Wo = (const float*)d_in[17];
  const float* dec_bo = (const float*)d_in[18];
  const float* ffe_W1 = (const float*)d_in[19];
  const float* ffe_b1 = (const float*)d_in[20];
  const float* ffe_W2 = (const float*)d_in[21];
  const float* ffe_b2 = (const float*)d_in[22];
  const float* ffd_W1 = (const float*)d_in[23];
  const float* ffd_b1 = (const float*)d_in[24];
  const float* ffd_W2 = (const float*)d_in[25];
  const float* ffd_b2 = (const float*)d_in[26];
  const float* ne_g   = (const float*)d_in[27];
  const float* ne_b   = (const float*)d_in[28];
  const float* nd_g   = (const float*)d_in[29];
  const float* nd_b   = (const float*)d_in[30];
  const float* out_W  = (const float*)d_in[31];
  const float* out_b  = (const float*)d_in[32];
  const float* temb_W = (const float*)d_in[33];
  const float* temb_b = (const float*)d_in[34];
  float* dout = (float*)d_out;

  float* ws = (float*)d_ws;
  size_t off = 0;
  auto alloc  = [&](size_t n){ n = (n+3)&~(size_t)3; float* p = ws + off; off += n; return p; };
  auto allocS = [&](size_t n){ size_t nf = ((n+1)/2 + 3)&~(size_t)3; short* p = (short*)(ws + off); off += nf; return p; };

  // encoder activations
  short* hshi = allocS((size_t)BT*DM);          // also hosts Wc-hi after KV build
  short* hslo = allocS((size_t)BT*DM);          // also hosts Wc-lo
  float* h    = alloc((size_t)BT*DM);           // also hosts dwo (split) in decoder
  float* hn   = h;
  float* t0   = alloc((size_t)BT*DM);           // also hosts dwq
  float* t1   = alloc((size_t)BT*DM);           // also hosts dwk
  float* t2   = alloc((size_t)BT*DM);           // also hosts dwv
  short* t3hi = allocS((size_t)BT*DM);          // also fw1h
  short* t3lo = allocS((size_t)BT*DM);          // also fw1l
  short* hnhi = allocS((size_t)BT*DM);          // also fw2h
  short* hnlo = allocS((size_t)BT*DM);          // also fw2l
  float* t4   = alloc((size_t)BT*DM);           // enc FFN2 out UNION setup temps UNION partA
  float* partA = t4;                            // dec: QKV partials (24 pl) / FFN1 partials (8 pl x DFFN)
  short* fmhi = (short*)t0;                     // enc FFN hidden split (aliases t0..t3lo)
  short* fmlo = fmhi + (size_t)BT*DFFN;
  // bf16 K/V cross-attn cache
  short* kcb  = allocS((size_t)NL*BT*DM);
  short* vcb  = allocS((size_t)NL*BT*DM);
  // split inputs
  short* xshi = allocS((size_t)BT*64);
  short* xslo = allocS((size_t)BT*64);
  short* iwhi = allocS((size_t)DM*64);
  short* iwlo = allocS((size_t)DM*64);
  // per-layer reused weight slots (encoder + KV build + Wc setup)
  short* w0hi = allocS((size_t)DM*DM); short* w0lo = allocS((size_t)DM*DM);
  short* w1hi = allocS((size_t)DM*DM); short* w1lo = allocS((size_t)DM*DM);
  short* w2hi = allocS((size_t)DM*DM); short* w2lo = allocS((size_t)DM*DM);
  short* w3hi = allocS((size_t)DM*DM); short* w3lo = allocS((size_t)DM*DM);
  short* wfhi = allocS((size_t)DFFN*DM); short* wflo = allocS((size_t)DFFN*DM);   // ffe_W1 (hoisted)
  short* wf2hi= allocS((size_t)DM*DFFN); short* wf2lo= allocS((size_t)DM*DFFN);   // ffe_W2 (hoisted)
  float* bqo  = alloc((size_t)NL*DM);
  float* zbuf = alloc((size_t)DM);
  // decoder buffers (packed rows r = i*4+b)
  float* dbuf = alloc((size_t)MD*DM);
  short* dphi = allocS((size_t)MD*DM);  short* dplo = allocS((size_t)MD*DM);  // step input
  short* dlhi = allocS((size_t)MD*DM);  short* dllo = allocS((size_t)MD*DM);  // LN out
  short* dahi = allocS((size_t)MD*DM);  short* dalo = allocS((size_t)MD*DM);  // attn out (self & cross)
  float* partB = alloc((size_t)16*MD*DM);   // Wc-Q partials (8) / FFN2 partials (16)
  float* partC = alloc((size_t)8*MD*DM);    // crossO partials (8) — residual source
  float* opart= alloc((size_t)BB*NH*CSPLIT*NSTEP*DKH);
  float* mlp  = alloc((size_t)BB*NH*CSPLIT*2*NSTEP);

  // decoder split weights aliased onto dead-after-encoder buffers
  const size_t MM = (size_t)DM*DM;
  short* dwq = (short*)t0;
  short* dwk = (short*)t1;
  short* dwv = (short*)t2;
  short* dwo = (short*)h;
  short* fw1h = t3hi; short* fw1l = t3lo;
  short* fw2h = hnhi; short* fw2l = hnlo;
  short* wch  = hshi; short* wcl  = hslo;        // combined Wc = Wq@Wo (split, row-major)
  float* wotf = t4;                              // setup temp: Wo^T f32
  float* wcf  = t4 + MM;                         // setup temp: Wc f32

  auto cvt = [&](const float* src, short* hi, short* lo, size_t n){
    split_kernel<<<(int)((n/8 + 255)/256), 256, 0, stream>>>(src, hi, lo, (int)(n/8));
  };

  cvt(x,    xshi, xslo, (size_t)BT*64);
  cvt(in_W, iwhi, iwlo, (size_t)DM*64);
  cvt(ffe_W1, wfhi,  wflo,  (size_t)DFFN*DM);    // layer-invariant: hoisted
  cvt(ffe_W2, wf2hi, wf2lo, (size_t)DM*DFFN);
  zero_kernel<<<(DM+255)/256, 256, 0, stream>>>(zbuf, DM);

  // input projection + PE -> split
  gemm_split<0,0><<<dim3(BT/128, DM/128), 256, 0, stream>>>(
      xshi, xslo, iwhi, iwlo, in_b, h, (short*)nullptr, (short*)nullptr, BT, DM, 64);
  add_pe_split<<<BT, 256, 0, stream>>>(h, hshi, hslo);

  // ---- encoder ----
  for (int l=0; l<NL; ++l) {
    const size_t wo = (size_t)l*DM*DM, bo_ = (size_t)l*DM;
    cvt(enc_Wq+wo, w0hi, w0lo, MM);
    cvt(enc_Wk+wo, w1hi, w1lo, MM);
    cvt(enc_Wv+wo, w2hi, w2lo, MM);
    cvt(enc_Wo+wo, w3hi, w3lo, MM);
    gemm_split<0,0><<<dim3(32,8),256,0,stream>>>(hshi, hslo, w0hi, w0lo, enc_bq+bo_,
        t0, (short*)nullptr, (short*)nullptr, BT, DM, DM);
    gemm_split<0,0><<<dim3(32,8),256,0,stream>>>(hshi, hslo, w1hi, w1lo, enc_bk+bo_,
        t1, (short*)nullptr, (short*)nullptr, BT, DM, DM);
    gemm_split<0,0><<<dim3(32,8),256,0,stream>>>(hshi, hslo, w2hi, w2lo, enc_bv+bo_,
        t2, (short*)nullptr, (short*)nullptr, BT, DM, DM);
    attn_enc<<<dim3(TT/256, BB*NH),256,0,stream>>>(t0, t1, t2, t3hi, t3lo);
    gemm_split<0,2><<<dim3(32,8),256,0,stream>>>(t3hi, t3lo, w3hi, w3lo, enc_bo+bo_,
        hn, hnhi, hnlo, BT, DM, DM);
    gemm_split<1,1><<<dim3(32,32),256,0,stream>>>(hnhi, hnlo, wfhi, wflo, ffe_b1,
        (float*)nullptr, fmhi, fmlo, BT, DFFN, DM);
    gemm_split<0,0><<<dim3(32,8),256,0,stream>>>(fmhi, fmlo, wf2hi, wf2lo, ffe_b2,
        t4, (short*)nullptr, (short*)nullptr, BT, DM, DFFN);
    ln_add_split<<<BT,256,0,stream>>>(hn, t4, ne_g, ne_b, hshi, hslo);
  }

  // ---- cross-attention K/V cache (bf16; last use of hshi/hslo as activations) ----
  for (int l=0; l<NL; ++l) {
    const size_t wo = (size_t)l*DM*DM, bo_ = (size_t)l*DM;
    cvt(dec_Wk+wo, w0hi, w0lo, MM);
    cvt(dec_Wv+wo, w1hi, w1lo, MM);
    gemm_split<0,3><<<dim3(32,8),256,0,stream>>>(hshi, hslo, w0hi, w0lo, dec_bk+bo_,
        (float*)nullptr, kcb+(size_t)l*BT*DM, (short*)nullptr, BT, DM, DM);
    gemm_split<0,3><<<dim3(32,8),256,0,stream>>>(hshi, hslo, w1hi, w1lo, dec_bv+bo_,
        (float*)nullptr, vcb+(size_t)l*BT*DM, (short*)nullptr, BT, DM, DM);
  }

  // ---- decoder weight setup (once; into dead encoder buffers) ----
  for (int l=0; l<NL; ++l) {
    const size_t wo = (size_t)l*DM*DM;
    cvt(dec_Wq+wo, dwq + (size_t)l*2*MM, dwq + (size_t)l*2*MM + MM, MM);
    cvt(dec_Wk+wo, dwk + (size_t)l*2*MM, dwk + (size_t)l*2*MM + MM, MM);
    cvt(dec_Wv+wo, dwv + (size_t)l*2*MM, dwv + (size_t)l*2*MM + MM, MM);
    cvt(dec_Wo+wo, dwo + (size_t)l*2*MM, dwo + (size_t)l*2*MM + MM, MM);
  }
  cvt(ffd_W1, fw1h, fw1l, (size_t)DFFN*DM);
  cvt(ffd_W2, fw2h, fw2l, (size_t)DM*DFFN);
  // combined cross-Q: Wc = Wq@Wo (row-major split into wch/wcl), bc = Wq@bo + bq
  for (int l=0; l<NL; ++l) {
    const size_t wo = (size_t)l*DM*DM, bo_ = (size_t)l*DM;
    k_transpose<<<1024, 256, 0, stream>>>(dec_Wo+wo, wotf);
    cvt(wotf,      w0hi, w0lo, MM);
    cvt(dec_Wq+wo, w1hi, w1lo, MM);
    gemm_split<0,0><<<dim3(8,8),256,0,stream>>>(w1hi, w1lo, w0hi, w0lo, zbuf,
        wcf, (short*)nullptr, (short*)nullptr, DM, DM, DM);
    k_bc<<<DM, 256, 0, stream>>>(dec_Wq+wo, dec_bo+bo_, dec_bq+bo_, bqo+bo_);
    cvt(wcf, wch + (size_t)l*MM, wcl + (size_t)l*MM, MM);
  }

  #define GD(MRv, grid, ...) do { switch(MRv){ \
    case 1: gemm_dec<1><<<grid,256,0,stream>>>(__VA_ARGS__); break; \
    case 2: gemm_dec<2><<<grid,256,0,stream>>>(__VA_ARGS__); break; \
    case 3: gemm_dec<3><<<grid,256,0,stream>>>(__VA_ARGS__); break; \
    case 4: gemm_dec<4><<<grid,256,0,stream>>>(__VA_ARGS__); break; \
    case 5: gemm_dec<5><<<grid,256,0,stream>>>(__VA_ARGS__); break; \
    default: gemm_dec<6><<<grid,256,0,stream>>>(__VA_ARGS__); break; } } while(0)
  #define GDR(MRv, AACT, grid, ...) do { switch(MRv){ \
    case 1: gemm_dec_r<1,AACT><<<grid,256,0,stream>>>(__VA_ARGS__); break; \
    case 2: gemm_dec_r<2,AACT><<<grid,256,0,stream>>>(__VA_ARGS__); break; \
    case 3: gemm_dec_r<3,AACT><<<grid,256,0,stream>>>(__VA_ARGS__); break; \
    case 4: gemm_dec_r<4,AACT><<<grid,256,0,stream>>>(__VA_ARGS__); break; \
    case 5: gemm_dec_r<5,AACT><<<grid,256,0,stream>>>(__VA_ARGS__); break; \
    default: gemm_dec_r<6,AACT><<<grid,256,0,stream>>>(__VA_ARGS__); break; } } while(0)

  // ---- decoder: 9 kernels/layer ----
  k_init0<<<BB, 256, 0, stream>>>(dphi, dplo);
  for (int s=0; s<NSTEP; ++s){
    const int n = s+1, rows = 4*n;
    const int Mt = (rows + 15) & ~15;
    const int MR = Mt >> 4;
    for (int l=0; l<NL; ++l){
      const short* qh = dwq + (size_t)l*2*MM; const short* ql = qh + MM;
      const short* kh = dwk + (size_t)l*2*MM; const short* kl = kh + MM;
      const short* vh = dwv + (size_t)l*2*MM; const short* vl = vh + MM;
      const short* oh = dwo + (size_t)l*2*MM; const short* ol = oh + MM;
      const short* ch = wch + (size_t)l*MM;   const short* cl = wcl + (size_t)l*MM;
      const float* lbq = dec_bq + (size_t)l*DM;
      const float* lbk = dec_bk + (size_t)l*DM;
      const float* lbv = dec_bv + (size_t)l*DM;
      const float* lbo = dec_bo + (size_t)l*DM;
      const float* lbc = bqo + (size_t)l*DM;
      const short* in_hi = (l==0) ? dphi : dlhi;
      const short* in_lo = (l==0) ? dplo : dllo;
      // self-attn QKV partials + attention with inline reduce
      GD(MR, dim3(8,8,3), in_hi,in_lo, qh,ql, kh,kl, vh,vl, partA, DM, DM, 8);
      attn_qkv<<<BB*NH,256,0,stream>>>(partA, lbq, lbk, lbv, dahi, dalo, n);
      // fused self-O + cross-Q (Wc) -> partB (8 planes)
      GD(MR, dim3(8,8,1), dahi,dalo, ch,cl, ch,cl, ch,cl, partB, DM, DM, 8);
      // cross-attention; Q reduced inline from partB
      attn_cross_part<<<dim3(CSPLIT, BB*NH),256,0,stream>>>(partB, lbc,
          kcb + (size_t)l*BT*DM, vcb + (size_t)l*BT*DM, opart, mlp, n);
      attn_cross_comb<<<dim3(BB*NH, 6),256,0,stream>>>(opart, mlp, dahi, dalo, n);
      // cross-O -> partC (8 planes; residual source for LN)
      GD(MR, dim3(8,8,1), dahi,dalo, oh,ol, oh,ol, oh,ol, partC, DM, DM, 8);
      // FFN1: A = reduce(partC)+lbo, inline split; -> partA (8 planes x DFFN)
      GDR(MR, 0, dim3(32,8), partC, lbo, fw1h, fw1l, partA, DFFN, DM, 8);
      // FFN2: A = reduce(partA)+fb1+ReLU, inline split; -> partB (16 planes)
      GDR(MR, 1, dim3(8,16), partA, ffd_b1, fw2h, fw2l, partB, DM, DFFN, 16);
      // LN: reduce partB(16)+fb2 + residual(reduce partC(8)+lbo)
      k_lnr<<<rows,256,0,stream>>>(partB, ffd_b2, partC, lbo, nd_g, nd_b,
          dbuf, dlhi, dllo);
    }
    k_out<<<BB, 256, 0, stream>>>(dbuf, out_W, out_b, temb_W, temb_b, dout,
        dphi, dplo, s);
  }
  #undef GD
  #undef GDR
}